// Round 1
// baseline (4547.600 us; speedup 1.0000x reference)
//
#include <hip/hip_runtime.h>

// GCN: H2 = relu(A @ relu(A@H @ W1 + b1) @ W2 + b2)
// A: COO (row, col, vals), E=1.6M edges, N=100k nodes, feat 64 -> 128 -> 128.
// Baseline: atomic-scatter SpMM + LDS-tiled f32 vector GEMM (no fp32 MFMA on CDNA4).

#define NFEAT 64
#define NHID 128

// ---------------- SpMM: out[row[e]] += vals[e] * Hin[col[e]] ----------------
// 64-feature variant: 16 float4 lanes per edge.
__global__ __launch_bounds__(256) void spmm64(
    const int* __restrict__ row, const int* __restrict__ col,
    const float* __restrict__ vals, const float* __restrict__ Hin,
    float* __restrict__ out, int n_edges) {
  int tid = blockIdx.x * 256 + threadIdx.x;
  int e = tid >> 4;        // edge index
  int f = tid & 15;        // float4 index within 64-feature row
  if (e >= n_edges) return;
  int c = col[e];
  int r = row[e];
  float v = vals[e];
  float4 h = ((const float4*)Hin)[(size_t)c * 16 + f];
  float* o = out + (size_t)r * 64 + f * 4;
  atomicAdd(o + 0, v * h.x);
  atomicAdd(o + 1, v * h.y);
  atomicAdd(o + 2, v * h.z);
  atomicAdd(o + 3, v * h.w);
}

// 128-feature variant: 32 float4 lanes per edge.
__global__ __launch_bounds__(256) void spmm128(
    const int* __restrict__ row, const int* __restrict__ col,
    const float* __restrict__ vals, const float* __restrict__ Hin,
    float* __restrict__ out, int n_edges) {
  int tid = blockIdx.x * 256 + threadIdx.x;
  int e = tid >> 5;
  int f = tid & 31;
  if (e >= n_edges) return;
  int c = col[e];
  int r = row[e];
  float v = vals[e];
  float4 h = ((const float4*)Hin)[(size_t)c * 32 + f];
  float* o = out + (size_t)r * 128 + f * 4;
  atomicAdd(o + 0, v * h.x);
  atomicAdd(o + 1, v * h.y);
  atomicAdd(o + 2, v * h.z);
  atomicAdd(o + 3, v * h.w);
}

// ---------------- GEMM1: out = relu(A(Nx64) @ W(64x128) + b) ----------------
// One wave per output row; W staged in LDS (32 KB). Lane j computes cols j, j+64.
__global__ __launch_bounds__(256) void gemm64_128_relu(
    const float* __restrict__ A, const float* __restrict__ W,
    const float* __restrict__ b, float* __restrict__ out, int n) {
  __shared__ float Wl[64 * 128];
  for (int i = threadIdx.x; i < 64 * 128 / 4; i += 256)
    ((float4*)Wl)[i] = ((const float4*)W)[i];
  __syncthreads();
  int wave = threadIdx.x >> 6;
  int lane = threadIdx.x & 63;
  int rowi = blockIdx.x * 4 + wave;
  if (rowi >= n) return;
  float a = A[(size_t)rowi * 64 + lane];  // lane k holds A[row][k]
  float acc0 = 0.f, acc1 = 0.f;
#pragma unroll
  for (int k = 0; k < 64; ++k) {
    float ak = __shfl(a, k);
    acc0 = fmaf(ak, Wl[k * 128 + lane], acc0);
    acc1 = fmaf(ak, Wl[k * 128 + 64 + lane], acc1);
  }
  acc0 = fmaxf(acc0 + b[lane], 0.f);
  acc1 = fmaxf(acc1 + b[64 + lane], 0.f);
  out[(size_t)rowi * 128 + lane] = acc0;
  out[(size_t)rowi * 128 + 64 + lane] = acc1;
}

// ---------------- GEMM2: out = relu(A(Nx128) @ W(128x128) + b) --------------
// In-place safe (A may alias out): full row read into regs before any write.
__global__ __launch_bounds__(256) void gemm128_128_relu(
    const float* __restrict__ A, const float* __restrict__ W,
    const float* __restrict__ b, float* __restrict__ out, int n) {
  __shared__ float Wl[128 * 128];  // 64 KB
  for (int i = threadIdx.x; i < 128 * 128 / 4; i += 256)
    ((float4*)Wl)[i] = ((const float4*)W)[i];
  __syncthreads();
  int wave = threadIdx.x >> 6;
  int lane = threadIdx.x & 63;
  int rowi = blockIdx.x * 4 + wave;
  if (rowi >= n) return;
  float a0 = A[(size_t)rowi * 128 + lane];        // A[row][0..63]
  float a1 = A[(size_t)rowi * 128 + 64 + lane];   // A[row][64..127]
  float acc0 = 0.f, acc1 = 0.f;
#pragma unroll
  for (int k = 0; k < 64; ++k) {
    float ak = __shfl(a0, k);
    acc0 = fmaf(ak, Wl[k * 128 + lane], acc0);
    acc1 = fmaf(ak, Wl[k * 128 + 64 + lane], acc1);
  }
#pragma unroll
  for (int k = 0; k < 64; ++k) {
    float ak = __shfl(a1, k);
    acc0 = fmaf(ak, Wl[(k + 64) * 128 + lane], acc0);
    acc1 = fmaf(ak, Wl[(k + 64) * 128 + 64 + lane], acc1);
  }
  acc0 = fmaxf(acc0 + b[lane], 0.f);
  acc1 = fmaxf(acc1 + b[64 + lane], 0.f);
  out[(size_t)rowi * 128 + lane] = acc0;
  out[(size_t)rowi * 128 + 64 + lane] = acc1;
}

extern "C" void kernel_launch(void* const* d_in, const int* in_sizes, int n_in,
                              void* d_out, int out_size, void* d_ws, size_t ws_size,
                              hipStream_t stream) {
  const int* row = (const int*)d_in[0];
  const int* col = (const int*)d_in[1];
  const float* vals = (const float*)d_in[2];
  const float* H = (const float*)d_in[3];
  const float* W1 = (const float*)d_in[4];
  const float* b1 = (const float*)d_in[5];
  const float* W2 = (const float*)d_in[6];
  const float* b2 = (const float*)d_in[7];
  float* out = (float*)d_out;

  const int n_edges = in_sizes[0];
  const int n_nodes = in_sizes[3] / NFEAT;

  // Workspace layout: AH (N*64 f32) | H1 (N*128 f32)   -> 76.8 MB
  float* AH = (float*)d_ws;
  float* H1 = AH + (size_t)n_nodes * NFEAT;

  // Zero the two accumulation buffers (ws and d_out are poisoned 0xAA).
  hipMemsetAsync(AH, 0, (size_t)n_nodes * NFEAT * sizeof(float), stream);
  hipMemsetAsync(out, 0, (size_t)n_nodes * NHID * sizeof(float), stream);

  // Layer 1: AH = A @ H ; H1 = relu(AH @ W1 + b1)
  {
    int total = n_edges * 16;
    spmm64<<<(total + 255) / 256, 256, 0, stream>>>(row, col, vals, H, AH, n_edges);
    gemm64_128_relu<<<(n_nodes + 3) / 4, 256, 0, stream>>>(AH, W1, b1, H1, n_nodes);
  }
  // Layer 2: AH1 (in d_out) = A @ H1 ; H2 = relu(AH1 @ W2 + b2) in-place.
  {
    int total = n_edges * 32;
    spmm128<<<(total + 255) / 256, 256, 0, stream>>>(row, col, vals, H1, out, n_edges);
    gemm128_128_relu<<<(n_nodes + 3) / 4, 256, 0, stream>>>(out, W2, b2, out, n_nodes);
  }
}

// Round 2
// 1029.805 us; speedup vs baseline: 4.4160x; 4.4160x over previous
//
#include <hip/hip_runtime.h>

// GCN: H2 = relu(A @ relu(A@H @ W1 + b1) @ W2 + b2)
// A: COO (row,col,vals), E=1.6M, N=100k, feats 64 -> 128 -> 128.
// R2: build CSR on-device (counting sort) -> gather SpMM, no f32 atomics.

#define NFEAT 64
#define NHID 128

// ---------------- CSR build ----------------
__global__ __launch_bounds__(256) void hist_kernel(
    const int* __restrict__ row, int* __restrict__ counts, int n_edges) {
  for (int e = blockIdx.x * 256 + threadIdx.x; e < n_edges; e += gridDim.x * 256)
    atomicAdd(&counts[row[e]], 1);
}

// Single-block exclusive scan of counts[0..n) -> row_ptr[0..n].
__global__ __launch_bounds__(1024) void scan_kernel(
    const int* __restrict__ counts, int* __restrict__ row_ptr, int n) {
  __shared__ int part[1024];
  int t = threadIdx.x;
  int chunk = (n + 1023) / 1024;
  int beg = t * chunk;
  int end = min(beg + chunk, n);
  int s = 0;
  for (int i = beg; i < end; ++i) s += counts[i];
  part[t] = s;
  __syncthreads();
  for (int off = 1; off < 1024; off <<= 1) {
    int v = (t >= off) ? part[t - off] : 0;
    __syncthreads();
    part[t] += v;
    __syncthreads();
  }
  int run = (t == 0) ? 0 : part[t - 1];
  for (int i = beg; i < end; ++i) {
    row_ptr[i] = run;
    run += counts[i];
  }
  if (t == 1023) row_ptr[n] = part[1023];
}

__global__ __launch_bounds__(256) void copy_ptr_kernel(
    const int* __restrict__ row_ptr, int* __restrict__ offsets, int n) {
  for (int i = blockIdx.x * 256 + threadIdx.x; i < n; i += gridDim.x * 256)
    offsets[i] = row_ptr[i];
}

// sedge[p] = (col, val) packed; p = next free slot in row bucket.
__global__ __launch_bounds__(256) void scatter_kernel(
    const int* __restrict__ row, const int* __restrict__ col,
    const float* __restrict__ vals, int* __restrict__ offsets,
    int2* __restrict__ sedge, int n_edges) {
  for (int e = blockIdx.x * 256 + threadIdx.x; e < n_edges; e += gridDim.x * 256) {
    int p = atomicAdd(&offsets[row[e]], 1);
    sedge[p] = make_int2(col[e], __float_as_int(vals[e]));
  }
}

// ---------------- CSR gather SpMM ----------------
// 64 feats: 16 lanes per row, one float4 per lane.
__global__ __launch_bounds__(256) void spmm64_csr(
    const int* __restrict__ row_ptr, const int2* __restrict__ sedge,
    const float* __restrict__ Hin, float* __restrict__ out, int n) {
  int tid = blockIdx.x * 256 + threadIdx.x;
  int r = tid >> 4;
  int f = tid & 15;
  if (r >= n) return;
  int beg = row_ptr[r], end = row_ptr[r + 1];
  float4 acc = make_float4(0.f, 0.f, 0.f, 0.f);
  for (int j = beg; j < end; ++j) {
    int2 ev = sedge[j];
    float v = __int_as_float(ev.y);
    float4 h = ((const float4*)Hin)[(size_t)ev.x * 16 + f];
    acc.x = fmaf(v, h.x, acc.x);
    acc.y = fmaf(v, h.y, acc.y);
    acc.z = fmaf(v, h.z, acc.z);
    acc.w = fmaf(v, h.w, acc.w);
  }
  ((float4*)out)[(size_t)r * 16 + f] = acc;
}

// 128 feats: 32 lanes per row.
__global__ __launch_bounds__(256) void spmm128_csr(
    const int* __restrict__ row_ptr, const int2* __restrict__ sedge,
    const float* __restrict__ Hin, float* __restrict__ out, int n) {
  int tid = blockIdx.x * 256 + threadIdx.x;
  int r = tid >> 5;
  int f = tid & 31;
  if (r >= n) return;
  int beg = row_ptr[r], end = row_ptr[r + 1];
  float4 acc = make_float4(0.f, 0.f, 0.f, 0.f);
  for (int j = beg; j < end; ++j) {
    int2 ev = sedge[j];
    float v = __int_as_float(ev.y);
    float4 h = ((const float4*)Hin)[(size_t)ev.x * 32 + f];
    acc.x = fmaf(v, h.x, acc.x);
    acc.y = fmaf(v, h.y, acc.y);
    acc.z = fmaf(v, h.z, acc.z);
    acc.w = fmaf(v, h.w, acc.w);
  }
  ((float4*)out)[(size_t)r * 32 + f] = acc;
}

// ---------------- fallback atomic SpMM (if ws too small) ----------------
__global__ __launch_bounds__(256) void spmm64_atomic(
    const int* __restrict__ row, const int* __restrict__ col,
    const float* __restrict__ vals, const float* __restrict__ Hin,
    float* __restrict__ out, int n_edges) {
  int tid = blockIdx.x * 256 + threadIdx.x;
  int e = tid >> 4, f = tid & 15;
  if (e >= n_edges) return;
  int c = col[e], r = row[e];
  float v = vals[e];
  float4 h = ((const float4*)Hin)[(size_t)c * 16 + f];
  float* o = out + (size_t)r * 64 + f * 4;
  atomicAdd(o + 0, v * h.x);
  atomicAdd(o + 1, v * h.y);
  atomicAdd(o + 2, v * h.z);
  atomicAdd(o + 3, v * h.w);
}

__global__ __launch_bounds__(256) void spmm128_atomic(
    const int* __restrict__ row, const int* __restrict__ col,
    const float* __restrict__ vals, const float* __restrict__ Hin,
    float* __restrict__ out, int n_edges) {
  int tid = blockIdx.x * 256 + threadIdx.x;
  int e = tid >> 5, f = tid & 31;
  if (e >= n_edges) return;
  int c = col[e], r = row[e];
  float v = vals[e];
  float4 h = ((const float4*)Hin)[(size_t)c * 32 + f];
  float* o = out + (size_t)r * 128 + f * 4;
  atomicAdd(o + 0, v * h.x);
  atomicAdd(o + 1, v * h.y);
  atomicAdd(o + 2, v * h.z);
  atomicAdd(o + 3, v * h.w);
}

// ---------------- dense GEMMs (f32 vector ALU, W in LDS) ----------------
__global__ __launch_bounds__(256) void gemm64_128_relu(
    const float* __restrict__ A, const float* __restrict__ W,
    const float* __restrict__ b, float* __restrict__ out, int n) {
  __shared__ float Wl[64 * 128];
  for (int i = threadIdx.x; i < 64 * 128 / 4; i += 256)
    ((float4*)Wl)[i] = ((const float4*)W)[i];
  __syncthreads();
  int wave = threadIdx.x >> 6;
  int lane = threadIdx.x & 63;
  int rowi = blockIdx.x * 4 + wave;
  if (rowi >= n) return;
  float a = A[(size_t)rowi * 64 + lane];
  float acc0 = 0.f, acc1 = 0.f;
#pragma unroll
  for (int k = 0; k < 64; ++k) {
    float ak = __shfl(a, k);
    acc0 = fmaf(ak, Wl[k * 128 + lane], acc0);
    acc1 = fmaf(ak, Wl[k * 128 + 64 + lane], acc1);
  }
  acc0 = fmaxf(acc0 + b[lane], 0.f);
  acc1 = fmaxf(acc1 + b[64 + lane], 0.f);
  out[(size_t)rowi * 128 + lane] = acc0;
  out[(size_t)rowi * 128 + 64 + lane] = acc1;
}

__global__ __launch_bounds__(256) void gemm128_128_relu(
    const float* __restrict__ A, const float* __restrict__ W,
    const float* __restrict__ b, float* __restrict__ out, int n) {
  __shared__ float Wl[128 * 128];  // 64 KB
  for (int i = threadIdx.x; i < 128 * 128 / 4; i += 256)
    ((float4*)Wl)[i] = ((const float4*)W)[i];
  __syncthreads();
  int wave = threadIdx.x >> 6;
  int lane = threadIdx.x & 63;
  int rowi = blockIdx.x * 4 + wave;
  if (rowi >= n) return;
  float a0 = A[(size_t)rowi * 128 + lane];
  float a1 = A[(size_t)rowi * 128 + 64 + lane];
  float acc0 = 0.f, acc1 = 0.f;
#pragma unroll
  for (int k = 0; k < 64; ++k) {
    float ak = __shfl(a0, k);
    acc0 = fmaf(ak, Wl[k * 128 + lane], acc0);
    acc1 = fmaf(ak, Wl[k * 128 + 64 + lane], acc1);
  }
#pragma unroll
  for (int k = 0; k < 64; ++k) {
    float ak = __shfl(a1, k);
    acc0 = fmaf(ak, Wl[(k + 64) * 128 + lane], acc0);
    acc1 = fmaf(ak, Wl[(k + 64) * 128 + 64 + lane], acc1);
  }
  acc0 = fmaxf(acc0 + b[lane], 0.f);
  acc1 = fmaxf(acc1 + b[64 + lane], 0.f);
  out[(size_t)rowi * 128 + lane] = acc0;
  out[(size_t)rowi * 128 + 64 + lane] = acc1;
}

extern "C" void kernel_launch(void* const* d_in, const int* in_sizes, int n_in,
                              void* d_out, int out_size, void* d_ws, size_t ws_size,
                              hipStream_t stream) {
  const int* row = (const int*)d_in[0];
  const int* col = (const int*)d_in[1];
  const float* vals = (const float*)d_in[2];
  const float* H = (const float*)d_in[3];
  const float* W1 = (const float*)d_in[4];
  const float* b1 = (const float*)d_in[5];
  const float* W2 = (const float*)d_in[6];
  const float* b2 = (const float*)d_in[7];
  float* out = (float*)d_out;

  const int n_edges = in_sizes[0];
  const int n_nodes = in_sizes[3] / NFEAT;

  // CSR-path workspace layout (16B-aligned slabs):
  // AH (N*64 f32) | H1 (N*128 f32) | sedge (E int2) | counts (N) | offsets (N) | row_ptr (N+1)
  size_t off = 0;
  float* AH = (float*)((char*)d_ws + off);      off += (size_t)n_nodes * NFEAT * 4;
  float* H1 = (float*)((char*)d_ws + off);      off += (size_t)n_nodes * NHID * 4;
  int2* sedge = (int2*)((char*)d_ws + off);     off += (size_t)n_edges * 8;
  int* counts = (int*)((char*)d_ws + off);      off += (size_t)n_nodes * 4;
  int* offsets = (int*)((char*)d_ws + off);     off += (size_t)n_nodes * 4;
  int* row_ptr = (int*)((char*)d_ws + off);     off += ((size_t)n_nodes + 1) * 4;
  const size_t needed = off;

  if (ws_size >= needed) {
    // ---- CSR path ----
    hipMemsetAsync(counts, 0, (size_t)n_nodes * sizeof(int), stream);
    hist_kernel<<<1024, 256, 0, stream>>>(row, counts, n_edges);
    scan_kernel<<<1, 1024, 0, stream>>>(counts, row_ptr, n_nodes);
    copy_ptr_kernel<<<256, 256, 0, stream>>>(row_ptr, offsets, n_nodes);
    scatter_kernel<<<1024, 256, 0, stream>>>(row, col, vals, offsets, sedge, n_edges);

    // Layer 1
    spmm64_csr<<<(n_nodes * 16 + 255) / 256, 256, 0, stream>>>(row_ptr, sedge, H, AH, n_nodes);
    gemm64_128_relu<<<(n_nodes + 3) / 4, 256, 0, stream>>>(AH, W1, b1, H1, n_nodes);
    // Layer 2 (AH1 in d_out, gemm in-place)
    spmm128_csr<<<(n_nodes * 32 + 255) / 256, 256, 0, stream>>>(row_ptr, sedge, H1, out, n_nodes);
    gemm128_128_relu<<<(n_nodes + 3) / 4, 256, 0, stream>>>(out, W2, b2, out, n_nodes);
  } else {
    // ---- fallback: atomic scatter path (R1) ----
    float* fAH = (float*)d_ws;
    float* fH1 = fAH + (size_t)n_nodes * NFEAT;
    hipMemsetAsync(fAH, 0, (size_t)n_nodes * NFEAT * sizeof(float), stream);
    hipMemsetAsync(out, 0, (size_t)n_nodes * NHID * sizeof(float), stream);
    spmm64_atomic<<<(n_edges * 16 + 255) / 256, 256, 0, stream>>>(row, col, vals, H, fAH, n_edges);
    gemm64_128_relu<<<(n_nodes + 3) / 4, 256, 0, stream>>>(fAH, W1, b1, fH1, n_nodes);
    spmm128_atomic<<<(n_edges * 32 + 255) / 256, 256, 0, stream>>>(row, col, vals, fH1, out, n_edges);
    gemm128_128_relu<<<(n_nodes + 3) / 4, 256, 0, stream>>>(out, W2, b2, out, n_nodes);
  }
}

// Round 3
// 803.637 us; speedup vs baseline: 5.6588x; 1.2814x over previous
//
#include <hip/hip_runtime.h>

// GCN: H2 = relu(A @ relu(A@H @ W1 + b1) @ W2 + b2)
// A: COO (row,col,vals), E=1.6M, N=100k, feats 64 -> 128 -> 128.
// R3: CSR gather SpMM + register-tiled f32 GEMM (8x8 per thread, 128x128 per block).

#define NFEAT 64
#define NHID 128

// ---------------- CSR build ----------------
__global__ __launch_bounds__(256) void hist_kernel(
    const int* __restrict__ row, int* __restrict__ counts, int n_edges) {
  for (int e = blockIdx.x * 256 + threadIdx.x; e < n_edges; e += gridDim.x * 256)
    atomicAdd(&counts[row[e]], 1);
}

// Single-block exclusive scan of counts[0..n) -> row_ptr[0..n] and offsets[0..n).
__global__ __launch_bounds__(1024) void scan_kernel(
    const int* __restrict__ counts, int* __restrict__ row_ptr,
    int* __restrict__ offsets, int n) {
  __shared__ int part[1024];
  int t = threadIdx.x;
  int chunk = (n + 1023) / 1024;
  int beg = t * chunk;
  int end = min(beg + chunk, n);
  int s = 0;
  for (int i = beg; i < end; ++i) s += counts[i];
  part[t] = s;
  __syncthreads();
  for (int off = 1; off < 1024; off <<= 1) {
    int v = (t >= off) ? part[t - off] : 0;
    __syncthreads();
    part[t] += v;
    __syncthreads();
  }
  int run = (t == 0) ? 0 : part[t - 1];
  for (int i = beg; i < end; ++i) {
    row_ptr[i] = run;
    offsets[i] = run;
    run += counts[i];
  }
  if (t == 1023) row_ptr[n] = part[1023];
}

// sedge[p] = (col, val) packed; p = next free slot in row bucket.
__global__ __launch_bounds__(256) void scatter_kernel(
    const int* __restrict__ row, const int* __restrict__ col,
    const float* __restrict__ vals, int* __restrict__ offsets,
    int2* __restrict__ sedge, int n_edges) {
  for (int e = blockIdx.x * 256 + threadIdx.x; e < n_edges; e += gridDim.x * 256) {
    int p = atomicAdd(&offsets[row[e]], 1);
    sedge[p] = make_int2(col[e], __float_as_int(vals[e]));
  }
}

// ---------------- CSR gather SpMM ----------------
__global__ __launch_bounds__(256) void spmm64_csr(
    const int* __restrict__ row_ptr, const int2* __restrict__ sedge,
    const float* __restrict__ Hin, float* __restrict__ out, int n) {
  int tid = blockIdx.x * 256 + threadIdx.x;
  int r = tid >> 4;
  int f = tid & 15;
  if (r >= n) return;
  int beg = row_ptr[r], end = row_ptr[r + 1];
  float4 acc = make_float4(0.f, 0.f, 0.f, 0.f);
#pragma unroll 2
  for (int j = beg; j < end; ++j) {
    int2 ev = sedge[j];
    float v = __int_as_float(ev.y);
    float4 h = ((const float4*)Hin)[(size_t)ev.x * 16 + f];
    acc.x = fmaf(v, h.x, acc.x);
    acc.y = fmaf(v, h.y, acc.y);
    acc.z = fmaf(v, h.z, acc.z);
    acc.w = fmaf(v, h.w, acc.w);
  }
  ((float4*)out)[(size_t)r * 16 + f] = acc;
}

__global__ __launch_bounds__(256) void spmm128_csr(
    const int* __restrict__ row_ptr, const int2* __restrict__ sedge,
    const float* __restrict__ Hin, float* __restrict__ out, int n) {
  int tid = blockIdx.x * 256 + threadIdx.x;
  int r = tid >> 5;
  int f = tid & 31;
  if (r >= n) return;
  int beg = row_ptr[r], end = row_ptr[r + 1];
  float4 acc = make_float4(0.f, 0.f, 0.f, 0.f);
#pragma unroll 2
  for (int j = beg; j < end; ++j) {
    int2 ev = sedge[j];
    float v = __int_as_float(ev.y);
    float4 h = ((const float4*)Hin)[(size_t)ev.x * 32 + f];
    acc.x = fmaf(v, h.x, acc.x);
    acc.y = fmaf(v, h.y, acc.y);
    acc.z = fmaf(v, h.z, acc.z);
    acc.w = fmaf(v, h.w, acc.w);
  }
  ((float4*)out)[(size_t)r * 32 + f] = acc;
}

// ---------------- fallback atomic SpMM (if ws too small) ----------------
__global__ __launch_bounds__(256) void spmm64_atomic(
    const int* __restrict__ row, const int* __restrict__ col,
    const float* __restrict__ vals, const float* __restrict__ Hin,
    float* __restrict__ out, int n_edges) {
  int tid = blockIdx.x * 256 + threadIdx.x;
  int e = tid >> 4, f = tid & 15;
  if (e >= n_edges) return;
  int c = col[e], r = row[e];
  float v = vals[e];
  float4 h = ((const float4*)Hin)[(size_t)c * 16 + f];
  float* o = out + (size_t)r * 64 + f * 4;
  atomicAdd(o + 0, v * h.x);
  atomicAdd(o + 1, v * h.y);
  atomicAdd(o + 2, v * h.z);
  atomicAdd(o + 3, v * h.w);
}

__global__ __launch_bounds__(256) void spmm128_atomic(
    const int* __restrict__ row, const int* __restrict__ col,
    const float* __restrict__ vals, const float* __restrict__ Hin,
    float* __restrict__ out, int n_edges) {
  int tid = blockIdx.x * 256 + threadIdx.x;
  int e = tid >> 5, f = tid & 31;
  if (e >= n_edges) return;
  int c = col[e], r = row[e];
  float v = vals[e];
  float4 h = ((const float4*)Hin)[(size_t)c * 32 + f];
  float* o = out + (size_t)r * 128 + f * 4;
  atomicAdd(o + 0, v * h.x);
  atomicAdd(o + 1, v * h.y);
  atomicAdd(o + 2, v * h.z);
  atomicAdd(o + 3, v * h.w);
}

// ---------------- register-tiled f32 GEMM + bias + relu ----------------
// C[n x 128] = relu(A[n x K] @ W[K x 128] + b), K in {64, 128}.
// Block: 256 threads, C-tile 128 rows x 128 cols. Thread (tx=t&15, ty=t>>4)
// computes rows {ty + 16i, i<8}, cols {4tx..4tx+3} and {64+4tx..64+4tx+3}.
// A staged transposed in LDS (pad 132), W staged row-major. Per k-step:
// 8 b32 (A, broadcast) + 2 b128 (W, consecutive) per 64 FMAs.
// In-place safe (A may alias out): a block touches only its own rows and all
// staging loads complete (syncthreads) before epilogue stores.
template <int K>
__global__ __launch_bounds__(256) void gemm_tiled_relu(
    const float* __restrict__ A, const float* __restrict__ W,
    const float* __restrict__ b, float* __restrict__ out, int n) {
  constexpr int KB = 32;
  constexpr int RP = 132;  // padded row length for transposed A tile
  __shared__ float As[KB][RP];   // As[k][r]  (16.9 KB)
  __shared__ float Ws[KB][128];  // Ws[k][c]  (16 KB)
  const int t = threadIdx.x;
  const int tx = t & 15, ty = t >> 4;
  const int r0 = blockIdx.x * 128;

  float4 acc0[8], acc1[8];
#pragma unroll
  for (int i = 0; i < 8; ++i) {
    acc0[i] = make_float4(0.f, 0.f, 0.f, 0.f);
    acc1[i] = make_float4(0.f, 0.f, 0.f, 0.f);
  }

  for (int k0 = 0; k0 < K; k0 += KB) {
    // stage W tile: KB x 128 floats = 1024 float4, 4 per thread
#pragma unroll
    for (int q = 0; q < 4; ++q) {
      int f = q * 256 + t;
      int kk = f >> 5, cv = f & 31;
      ((float4*)&Ws[kk][0])[cv] =
          ((const float4*)(W + (size_t)(k0 + kk) * 128))[cv];
    }
    // stage A tile transposed: 128 rows x KB cols = 1024 float4, 4 per thread
#pragma unroll
    for (int q = 0; q < 4; ++q) {
      int f = q * 256 + t;  // f = r*8 + kv
      int r = f >> 3, kv = f & 7;
      float4 av = make_float4(0.f, 0.f, 0.f, 0.f);
      if (r0 + r < n) av = ((const float4*)(A + (size_t)(r0 + r) * K + k0))[kv];
      As[4 * kv + 0][r] = av.x;
      As[4 * kv + 1][r] = av.y;
      As[4 * kv + 2][r] = av.z;
      As[4 * kv + 3][r] = av.w;
    }
    __syncthreads();
#pragma unroll
    for (int k = 0; k < KB; ++k) {
      float4 w0 = *((const float4*)&Ws[k][4 * tx]);
      float4 w1 = *((const float4*)&Ws[k][64 + 4 * tx]);
#pragma unroll
      for (int i = 0; i < 8; ++i) {
        float a = As[k][ty + 16 * i];
        acc0[i].x = fmaf(a, w0.x, acc0[i].x);
        acc0[i].y = fmaf(a, w0.y, acc0[i].y);
        acc0[i].z = fmaf(a, w0.z, acc0[i].z);
        acc0[i].w = fmaf(a, w0.w, acc0[i].w);
        acc1[i].x = fmaf(a, w1.x, acc1[i].x);
        acc1[i].y = fmaf(a, w1.y, acc1[i].y);
        acc1[i].z = fmaf(a, w1.z, acc1[i].z);
        acc1[i].w = fmaf(a, w1.w, acc1[i].w);
      }
    }
    __syncthreads();
  }

  float4 bb0 = ((const float4*)b)[tx];
  float4 bb1 = ((const float4*)(b + 64))[tx];
#pragma unroll
  for (int i = 0; i < 8; ++i) {
    int r = r0 + ty + 16 * i;
    if (r >= n) continue;
    float4 o0, o1;
    o0.x = fmaxf(acc0[i].x + bb0.x, 0.f);
    o0.y = fmaxf(acc0[i].y + bb0.y, 0.f);
    o0.z = fmaxf(acc0[i].z + bb0.z, 0.f);
    o0.w = fmaxf(acc0[i].w + bb0.w, 0.f);
    o1.x = fmaxf(acc1[i].x + bb1.x, 0.f);
    o1.y = fmaxf(acc1[i].y + bb1.y, 0.f);
    o1.z = fmaxf(acc1[i].z + bb1.z, 0.f);
    o1.w = fmaxf(acc1[i].w + bb1.w, 0.f);
    ((float4*)(out + (size_t)r * 128))[tx] = o0;
    ((float4*)(out + (size_t)r * 128 + 64))[tx] = o1;
  }
}

extern "C" void kernel_launch(void* const* d_in, const int* in_sizes, int n_in,
                              void* d_out, int out_size, void* d_ws, size_t ws_size,
                              hipStream_t stream) {
  const int* row = (const int*)d_in[0];
  const int* col = (const int*)d_in[1];
  const float* vals = (const float*)d_in[2];
  const float* H = (const float*)d_in[3];
  const float* W1 = (const float*)d_in[4];
  const float* b1 = (const float*)d_in[5];
  const float* W2 = (const float*)d_in[6];
  const float* b2 = (const float*)d_in[7];
  float* out = (float*)d_out;

  const int n_edges = in_sizes[0];
  const int n_nodes = in_sizes[3] / NFEAT;
  const int gemm_grid = (n_nodes + 127) / 128;

  // Workspace layout:
  // AH (N*64 f32) | H1 (N*128 f32) | sedge (E int2) | counts (N) | offsets (N) | row_ptr (N+1)
  size_t off = 0;
  float* AH = (float*)((char*)d_ws + off);   off += (size_t)n_nodes * NFEAT * 4;
  float* H1 = (float*)((char*)d_ws + off);   off += (size_t)n_nodes * NHID * 4;
  int2* sedge = (int2*)((char*)d_ws + off);  off += (size_t)n_edges * 8;
  int* counts = (int*)((char*)d_ws + off);   off += (size_t)n_nodes * 4;
  int* offsets = (int*)((char*)d_ws + off);  off += (size_t)n_nodes * 4;
  int* row_ptr = (int*)((char*)d_ws + off);  off += ((size_t)n_nodes + 1) * 4;
  const size_t needed = off;

  if (ws_size >= needed) {
    // ---- CSR path ----
    hipMemsetAsync(counts, 0, (size_t)n_nodes * sizeof(int), stream);
    hist_kernel<<<1024, 256, 0, stream>>>(row, counts, n_edges);
    scan_kernel<<<1, 1024, 0, stream>>>(counts, row_ptr, offsets, n_nodes);
    scatter_kernel<<<1024, 256, 0, stream>>>(row, col, vals, offsets, sedge, n_edges);

    // Layer 1
    spmm64_csr<<<(n_nodes * 16 + 255) / 256, 256, 0, stream>>>(row_ptr, sedge, H, AH, n_nodes);
    gemm_tiled_relu<64><<<gemm_grid, 256, 0, stream>>>(AH, W1, b1, H1, n_nodes);
    // Layer 2 (AH1 in d_out, gemm in-place)
    spmm128_csr<<<(n_nodes * 32 + 255) / 256, 256, 0, stream>>>(row_ptr, sedge, H1, out, n_nodes);
    gemm_tiled_relu<128><<<gemm_grid, 256, 0, stream>>>(out, W2, b2, out, n_nodes);
  } else {
    // ---- fallback: atomic scatter path ----
    float* fAH = (float*)d_ws;
    float* fH1 = fAH + (size_t)n_nodes * NFEAT;
    hipMemsetAsync(fAH, 0, (size_t)n_nodes * NFEAT * sizeof(float), stream);
    hipMemsetAsync(out, 0, (size_t)n_nodes * NHID * sizeof(float), stream);
    spmm64_atomic<<<(n_edges * 16 + 255) / 256, 256, 0, stream>>>(row, col, vals, H, fAH, n_edges);
    gemm_tiled_relu<64><<<gemm_grid, 256, 0, stream>>>(fAH, W1, b1, fH1, n_nodes);
    spmm128_atomic<<<(n_edges * 32 + 255) / 256, 256, 0, stream>>>(row, col, vals, fH1, out, n_edges);
    gemm_tiled_relu<128><<<gemm_grid, 256, 0, stream>>>(out, W2, b2, out, n_nodes);
  }
}

// Round 4
// 596.782 us; speedup vs baseline: 7.6202x; 1.3466x over previous
//
#include <hip/hip_runtime.h>

// GCN: H2 = relu(A @ relu(A@H @ W1 + b1) @ W2 + b2)
// A: COO (row,col,vals), E=1.6M, N=100k, feats 64 -> 128 -> 128.
// R4: hierarchical 3-pass scan (the R3 single-block scan was 230us at 0.15% occupancy).

#define NFEAT 64
#define NHID 128
#define SCAN_BLOCKS 128
#define SCAN_T 256

// ---------------- CSR build ----------------
__global__ __launch_bounds__(256) void hist_kernel(
    const int* __restrict__ row, int* __restrict__ counts, int n_edges) {
  for (int e = blockIdx.x * 256 + threadIdx.x; e < n_edges; e += gridDim.x * 256)
    atomicAdd(&counts[row[e]], 1);
}

// Pass 1: per-block reduction of a contiguous chunk of counts -> block_sums.
__global__ __launch_bounds__(SCAN_T) void scan_pass1(
    const int* __restrict__ counts, int* __restrict__ block_sums, int n) {
  int chunk = (n + SCAN_BLOCKS - 1) / SCAN_BLOCKS;
  int beg = blockIdx.x * chunk;
  int end = min(beg + chunk, n);
  int per = (chunk + SCAN_T - 1) / SCAN_T;
  int tb = beg + threadIdx.x * per;
  int te = min(tb + per, end);
  int s = 0;
  for (int i = tb; i < te; ++i) s += counts[i];
  __shared__ int sm[SCAN_T];
  sm[threadIdx.x] = s;
  __syncthreads();
  for (int off = SCAN_T / 2; off > 0; off >>= 1) {
    if (threadIdx.x < off) sm[threadIdx.x] += sm[threadIdx.x + off];
    __syncthreads();
  }
  if (threadIdx.x == 0) block_sums[blockIdx.x] = sm[0];
}

// Pass 2: single small block turns block_sums into its exclusive prefix.
__global__ __launch_bounds__(SCAN_BLOCKS) void scan_pass2(
    int* __restrict__ block_sums, int nb) {
  __shared__ int sm[SCAN_BLOCKS];
  int t = threadIdx.x;
  int v = (t < nb) ? block_sums[t] : 0;
  sm[t] = v;
  __syncthreads();
  for (int off = 1; off < SCAN_BLOCKS; off <<= 1) {
    int u = (t >= off) ? sm[t - off] : 0;
    __syncthreads();
    sm[t] += u;
    __syncthreads();
  }
  if (t < nb) block_sums[t] = sm[t] - v;  // exclusive
}

// Pass 3: block-local exclusive scan + block offset -> row_ptr, offsets.
__global__ __launch_bounds__(SCAN_T) void scan_pass3(
    const int* __restrict__ counts, const int* __restrict__ block_sums,
    int* __restrict__ row_ptr, int* __restrict__ offsets, int n) {
  int chunk = (n + SCAN_BLOCKS - 1) / SCAN_BLOCKS;
  int beg = blockIdx.x * chunk;
  int end = min(beg + chunk, n);
  int per = (chunk + SCAN_T - 1) / SCAN_T;
  int t = threadIdx.x;
  int tb = beg + t * per;
  int te = min(tb + per, end);
  int s = 0;
  for (int i = tb; i < te; ++i) s += counts[i];
  __shared__ int sm[SCAN_T];
  sm[t] = s;
  __syncthreads();
  for (int off = 1; off < SCAN_T; off <<= 1) {
    int u = (t >= off) ? sm[t - off] : 0;
    __syncthreads();
    sm[t] += u;
    __syncthreads();
  }
  int run = block_sums[blockIdx.x] + sm[t] - s;  // exclusive prefix at tb
  for (int i = tb; i < te; ++i) {
    int c = counts[i];
    row_ptr[i] = run;
    offsets[i] = run;
    run += c;
  }
  if (blockIdx.x == SCAN_BLOCKS - 1 && t == SCAN_T - 1) row_ptr[n] = run;
}

// sedge[p] = (col, val) packed; p = next free slot in row bucket.
__global__ __launch_bounds__(256) void scatter_kernel(
    const int* __restrict__ row, const int* __restrict__ col,
    const float* __restrict__ vals, int* __restrict__ offsets,
    int2* __restrict__ sedge, int n_edges) {
  for (int e = blockIdx.x * 256 + threadIdx.x; e < n_edges; e += gridDim.x * 256) {
    int p = atomicAdd(&offsets[row[e]], 1);
    sedge[p] = make_int2(col[e], __float_as_int(vals[e]));
  }
}

// ---------------- CSR gather SpMM ----------------
__global__ __launch_bounds__(256) void spmm64_csr(
    const int* __restrict__ row_ptr, const int2* __restrict__ sedge,
    const float* __restrict__ Hin, float* __restrict__ out, int n) {
  int tid = blockIdx.x * 256 + threadIdx.x;
  int r = tid >> 4;
  int f = tid & 15;
  if (r >= n) return;
  int beg = row_ptr[r], end = row_ptr[r + 1];
  float4 acc = make_float4(0.f, 0.f, 0.f, 0.f);
#pragma unroll 2
  for (int j = beg; j < end; ++j) {
    int2 ev = sedge[j];
    float v = __int_as_float(ev.y);
    float4 h = ((const float4*)Hin)[(size_t)ev.x * 16 + f];
    acc.x = fmaf(v, h.x, acc.x);
    acc.y = fmaf(v, h.y, acc.y);
    acc.z = fmaf(v, h.z, acc.z);
    acc.w = fmaf(v, h.w, acc.w);
  }
  ((float4*)out)[(size_t)r * 16 + f] = acc;
}

__global__ __launch_bounds__(256) void spmm128_csr(
    const int* __restrict__ row_ptr, const int2* __restrict__ sedge,
    const float* __restrict__ Hin, float* __restrict__ out, int n) {
  int tid = blockIdx.x * 256 + threadIdx.x;
  int r = tid >> 5;
  int f = tid & 31;
  if (r >= n) return;
  int beg = row_ptr[r], end = row_ptr[r + 1];
  float4 acc = make_float4(0.f, 0.f, 0.f, 0.f);
#pragma unroll 2
  for (int j = beg; j < end; ++j) {
    int2 ev = sedge[j];
    float v = __int_as_float(ev.y);
    float4 h = ((const float4*)Hin)[(size_t)ev.x * 32 + f];
    acc.x = fmaf(v, h.x, acc.x);
    acc.y = fmaf(v, h.y, acc.y);
    acc.z = fmaf(v, h.z, acc.z);
    acc.w = fmaf(v, h.w, acc.w);
  }
  ((float4*)out)[(size_t)r * 32 + f] = acc;
}

// ---------------- fallback atomic SpMM (if ws too small) ----------------
__global__ __launch_bounds__(256) void spmm64_atomic(
    const int* __restrict__ row, const int* __restrict__ col,
    const float* __restrict__ vals, const float* __restrict__ Hin,
    float* __restrict__ out, int n_edges) {
  int tid = blockIdx.x * 256 + threadIdx.x;
  int e = tid >> 4, f = tid & 15;
  if (e >= n_edges) return;
  int c = col[e], r = row[e];
  float v = vals[e];
  float4 h = ((const float4*)Hin)[(size_t)c * 16 + f];
  float* o = out + (size_t)r * 64 + f * 4;
  atomicAdd(o + 0, v * h.x);
  atomicAdd(o + 1, v * h.y);
  atomicAdd(o + 2, v * h.z);
  atomicAdd(o + 3, v * h.w);
}

__global__ __launch_bounds__(256) void spmm128_atomic(
    const int* __restrict__ row, const int* __restrict__ col,
    const float* __restrict__ vals, const float* __restrict__ Hin,
    float* __restrict__ out, int n_edges) {
  int tid = blockIdx.x * 256 + threadIdx.x;
  int e = tid >> 5, f = tid & 31;
  if (e >= n_edges) return;
  int c = col[e], r = row[e];
  float v = vals[e];
  float4 h = ((const float4*)Hin)[(size_t)c * 32 + f];
  float* o = out + (size_t)r * 128 + f * 4;
  atomicAdd(o + 0, v * h.x);
  atomicAdd(o + 1, v * h.y);
  atomicAdd(o + 2, v * h.z);
  atomicAdd(o + 3, v * h.w);
}

// ---------------- register-tiled f32 GEMM + bias + relu ----------------
// C[n x 128] = relu(A[n x K] @ W[K x 128] + b), K in {64, 128}.
// Block: 256 threads, C-tile 128x128; thread (tx,ty) does 8 rows x 8 cols.
// Per k-step: 8 b32 (A bcast) + 2 b128 (W) per 64 FMAs. In-place safe.
template <int K>
__global__ __launch_bounds__(256) void gemm_tiled_relu(
    const float* __restrict__ A, const float* __restrict__ W,
    const float* __restrict__ b, float* __restrict__ out, int n) {
  constexpr int KB = 32;
  constexpr int RP = 132;
  __shared__ float As[KB][RP];
  __shared__ float Ws[KB][128];
  const int t = threadIdx.x;
  const int tx = t & 15, ty = t >> 4;
  const int r0 = blockIdx.x * 128;

  float4 acc0[8], acc1[8];
#pragma unroll
  for (int i = 0; i < 8; ++i) {
    acc0[i] = make_float4(0.f, 0.f, 0.f, 0.f);
    acc1[i] = make_float4(0.f, 0.f, 0.f, 0.f);
  }

  for (int k0 = 0; k0 < K; k0 += KB) {
#pragma unroll
    for (int q = 0; q < 4; ++q) {
      int f = q * 256 + t;
      int kk = f >> 5, cv = f & 31;
      ((float4*)&Ws[kk][0])[cv] =
          ((const float4*)(W + (size_t)(k0 + kk) * 128))[cv];
    }
#pragma unroll
    for (int q = 0; q < 4; ++q) {
      int f = q * 256 + t;
      int r = f >> 3, kv = f & 7;
      float4 av = make_float4(0.f, 0.f, 0.f, 0.f);
      if (r0 + r < n) av = ((const float4*)(A + (size_t)(r0 + r) * K + k0))[kv];
      As[4 * kv + 0][r] = av.x;
      As[4 * kv + 1][r] = av.y;
      As[4 * kv + 2][r] = av.z;
      As[4 * kv + 3][r] = av.w;
    }
    __syncthreads();
#pragma unroll
    for (int k = 0; k < KB; ++k) {
      float4 w0 = *((const float4*)&Ws[k][4 * tx]);
      float4 w1 = *((const float4*)&Ws[k][64 + 4 * tx]);
#pragma unroll
      for (int i = 0; i < 8; ++i) {
        float a = As[k][ty + 16 * i];
        acc0[i].x = fmaf(a, w0.x, acc0[i].x);
        acc0[i].y = fmaf(a, w0.y, acc0[i].y);
        acc0[i].z = fmaf(a, w0.z, acc0[i].z);
        acc0[i].w = fmaf(a, w0.w, acc0[i].w);
        acc1[i].x = fmaf(a, w1.x, acc1[i].x);
        acc1[i].y = fmaf(a, w1.y, acc1[i].y);
        acc1[i].z = fmaf(a, w1.z, acc1[i].z);
        acc1[i].w = fmaf(a, w1.w, acc1[i].w);
      }
    }
    __syncthreads();
  }

  float4 bb0 = ((const float4*)b)[tx];
  float4 bb1 = ((const float4*)(b + 64))[tx];
#pragma unroll
  for (int i = 0; i < 8; ++i) {
    int r = r0 + ty + 16 * i;
    if (r >= n) continue;
    float4 o0, o1;
    o0.x = fmaxf(acc0[i].x + bb0.x, 0.f);
    o0.y = fmaxf(acc0[i].y + bb0.y, 0.f);
    o0.z = fmaxf(acc0[i].z + bb0.z, 0.f);
    o0.w = fmaxf(acc0[i].w + bb0.w, 0.f);
    o1.x = fmaxf(acc1[i].x + bb1.x, 0.f);
    o1.y = fmaxf(acc1[i].y + bb1.y, 0.f);
    o1.z = fmaxf(acc1[i].z + bb1.z, 0.f);
    o1.w = fmaxf(acc1[i].w + bb1.w, 0.f);
    ((float4*)(out + (size_t)r * 128))[tx] = o0;
    ((float4*)(out + (size_t)r * 128 + 64))[tx] = o1;
  }
}

extern "C" void kernel_launch(void* const* d_in, const int* in_sizes, int n_in,
                              void* d_out, int out_size, void* d_ws, size_t ws_size,
                              hipStream_t stream) {
  const int* row = (const int*)d_in[0];
  const int* col = (const int*)d_in[1];
  const float* vals = (const float*)d_in[2];
  const float* H = (const float*)d_in[3];
  const float* W1 = (const float*)d_in[4];
  const float* b1 = (const float*)d_in[5];
  const float* W2 = (const float*)d_in[6];
  const float* b2 = (const float*)d_in[7];
  float* out = (float*)d_out;

  const int n_edges = in_sizes[0];
  const int n_nodes = in_sizes[3] / NFEAT;
  const int gemm_grid = (n_nodes + 127) / 128;

  // Workspace layout:
  // AH (N*64) | H1 (N*128) | sedge (E int2) | counts (N) | offsets (N) | row_ptr (N+1) | block_sums (128)
  size_t off = 0;
  float* AH = (float*)((char*)d_ws + off);   off += (size_t)n_nodes * NFEAT * 4;
  float* H1 = (float*)((char*)d_ws + off);   off += (size_t)n_nodes * NHID * 4;
  int2* sedge = (int2*)((char*)d_ws + off);  off += (size_t)n_edges * 8;
  int* counts = (int*)((char*)d_ws + off);   off += (size_t)n_nodes * 4;
  int* offsets = (int*)((char*)d_ws + off);  off += (size_t)n_nodes * 4;
  int* row_ptr = (int*)((char*)d_ws + off);  off += ((size_t)n_nodes + 1) * 4;
  int* block_sums = (int*)((char*)d_ws + off); off += SCAN_BLOCKS * 4;
  const size_t needed = off;

  if (ws_size >= needed) {
    // ---- CSR path ----
    hipMemsetAsync(counts, 0, (size_t)n_nodes * sizeof(int), stream);
    hist_kernel<<<1024, 256, 0, stream>>>(row, counts, n_edges);
    scan_pass1<<<SCAN_BLOCKS, SCAN_T, 0, stream>>>(counts, block_sums, n_nodes);
    scan_pass2<<<1, SCAN_BLOCKS, 0, stream>>>(block_sums, SCAN_BLOCKS);
    scan_pass3<<<SCAN_BLOCKS, SCAN_T, 0, stream>>>(counts, block_sums, row_ptr, offsets, n_nodes);
    scatter_kernel<<<1024, 256, 0, stream>>>(row, col, vals, offsets, sedge, n_edges);

    // Layer 1
    spmm64_csr<<<(n_nodes * 16 + 255) / 256, 256, 0, stream>>>(row_ptr, sedge, H, AH, n_nodes);
    gemm_tiled_relu<64><<<gemm_grid, 256, 0, stream>>>(AH, W1, b1, H1, n_nodes);
    // Layer 2 (AH1 in d_out, gemm in-place)
    spmm128_csr<<<(n_nodes * 32 + 255) / 256, 256, 0, stream>>>(row_ptr, sedge, H1, out, n_nodes);
    gemm_tiled_relu<128><<<gemm_grid, 256, 0, stream>>>(out, W2, b2, out, n_nodes);
  } else {
    // ---- fallback: atomic scatter path ----
    float* fAH = (float*)d_ws;
    float* fH1 = fAH + (size_t)n_nodes * NFEAT;
    hipMemsetAsync(fAH, 0, (size_t)n_nodes * NFEAT * sizeof(float), stream);
    hipMemsetAsync(out, 0, (size_t)n_nodes * NHID * sizeof(float), stream);
    spmm64_atomic<<<(n_edges * 16 + 255) / 256, 256, 0, stream>>>(row, col, vals, H, fAH, n_edges);
    gemm_tiled_relu<64><<<gemm_grid, 256, 0, stream>>>(fAH, W1, b1, fH1, n_nodes);
    spmm128_atomic<<<(n_edges * 32 + 255) / 256, 256, 0, stream>>>(row, col, vals, fH1, out, n_edges);
    gemm_tiled_relu<128><<<gemm_grid, 256, 0, stream>>>(out, W2, b2, out, n_nodes);
  }
}

// Round 5
// 470.370 us; speedup vs baseline: 9.6681x; 1.2688x over previous
//
#include <hip/hip_runtime.h>

// GCN: H2 = relu(A @ relu(A@H @ W1 + b1) @ W2 + b2)
// A: COO (row,col,vals), E=1.6M, N=100k, feats 64 -> 128 -> 128.
// R5: CSR build via 2-pass bucket sort (512-row buckets) — kills the 8x write
// amplification of the R4 global scatter (WRITE_SIZE 100MB for 12.8MB output).

#define NFEAT 64
#define NHID 128
#define BSHIFT 9              // 512 rows per bucket
#define BROWS (1 << BSHIFT)
#define NB_MAX 256            // supports n_nodes <= 131072 (also 17-bit col pack)

// ---------------- bucket histogram (LDS-aggregated) ----------------
__global__ __launch_bounds__(256) void bhist_kernel(
    const int* __restrict__ row, int* __restrict__ bcnt, int n_edges, int nb) {
  __shared__ int h[NB_MAX];
  for (int i = threadIdx.x; i < NB_MAX; i += 256) h[i] = 0;
  __syncthreads();
  for (int e = blockIdx.x * 256 + threadIdx.x; e < n_edges; e += gridDim.x * 256)
    atomicAdd(&h[row[e] >> BSHIFT], 1);
  __syncthreads();
  for (int i = threadIdx.x; i < nb; i += 256)
    if (h[i]) atomicAdd(&bcnt[i], h[i]);
}

// ---------------- bucket scan -> bbase[nb+1], cur[nb], row_ptr[n] ----------------
__global__ __launch_bounds__(NB_MAX) void bscan_kernel(
    const int* __restrict__ bcnt, int* __restrict__ bbase, int* __restrict__ cur,
    int* __restrict__ row_ptr, int nb, int n) {
  __shared__ int sm[NB_MAX];
  int t = threadIdx.x;
  int v = (t < nb) ? bcnt[t] : 0;
  sm[t] = v;
  __syncthreads();
  for (int off = 1; off < NB_MAX; off <<= 1) {
    int u = (t >= off) ? sm[t - off] : 0;
    __syncthreads();
    sm[t] += u;
    __syncthreads();
  }
  if (t < nb) {
    bbase[t] = sm[t] - v;
    cur[t] = sm[t] - v;
  }
  if (t == nb - 1) {
    bbase[nb] = sm[t];
    row_ptr[n] = sm[t];
  }
}

// ---------------- pass A: multi-split partition into buckets ----------------
// bedge[p] = ((rl<<17)|col, val) with rl = row within bucket. Writes are
// block-exclusive contiguous runs -> near-1x write amplification.
__global__ __launch_bounds__(256) void partition_kernel(
    const int* __restrict__ row, const int* __restrict__ col,
    const float* __restrict__ vals, int* __restrict__ cur,
    int2* __restrict__ bedge, int n_edges) {
  __shared__ int h[NB_MAX], base[NB_MAX], rk[NB_MAX];
  for (int i = threadIdx.x; i < NB_MAX; i += 256) {
    h[i] = 0;
    rk[i] = 0;
  }
  __syncthreads();
  const int start = blockIdx.x * 256 + threadIdx.x;
  const int step = gridDim.x * 256;
  for (int e = start; e < n_edges; e += step)
    atomicAdd(&h[row[e] >> BSHIFT], 1);
  __syncthreads();
  for (int i = threadIdx.x; i < NB_MAX; i += 256)
    base[i] = h[i] ? atomicAdd(&cur[i], h[i]) : 0;
  __syncthreads();
  for (int e = start; e < n_edges; e += step) {
    int r = row[e];
    int b = r >> BSHIFT;
    int rl = r & (BROWS - 1);
    int p = base[b] + atomicAdd(&rk[b], 1);
    bedge[p] = make_int2((rl << 17) | col[e], __float_as_int(vals[e]));
  }
}

// ---------------- pass B: per-bucket exact CSR ----------------
// One block per bucket: LDS row-hist + scan -> row_ptr; rank-scatter edges into
// the bucket's contiguous sedge region (<=~80KB, L2-resident -> full line fill).
__global__ __launch_bounds__(512) void bucket_csr_kernel(
    const int* __restrict__ bbase, const int2* __restrict__ bedge,
    int* __restrict__ row_ptr, int2* __restrict__ sedge, int n) {
  __shared__ int cnt[BROWS];
  __shared__ int sm[BROWS];
  const int b = blockIdx.x;
  const int t = threadIdx.x;
  const int beg = bbase[b], end = bbase[b + 1];
  cnt[t] = 0;
  __syncthreads();
  for (int j = beg + t; j < end; j += 512)
    atomicAdd(&cnt[((unsigned)bedge[j].x) >> 17], 1);
  __syncthreads();
  int v = cnt[t];
  sm[t] = v;
  __syncthreads();
  for (int off = 1; off < BROWS; off <<= 1) {
    int u = (t >= off) ? sm[t - off] : 0;
    __syncthreads();
    sm[t] += u;
    __syncthreads();
  }
  {
    int incl = sm[t];
    __syncthreads();
    sm[t] = incl - v;  // exclusive local base
  }
  int r = (b << BSHIFT) + t;
  if (r < n) row_ptr[r] = beg + sm[t];
  cnt[t] = 0;
  __syncthreads();
  for (int j = beg + t; j < end; j += 512) {
    int2 ev = bedge[j];
    int rl = ((unsigned)ev.x) >> 17;
    int rank = atomicAdd(&cnt[rl], 1);
    sedge[beg + sm[rl] + rank] = make_int2(ev.x & 0x1FFFF, ev.y);
  }
}

// ---------------- CSR gather SpMM ----------------
__global__ __launch_bounds__(256) void spmm64_csr(
    const int* __restrict__ row_ptr, const int2* __restrict__ sedge,
    const float* __restrict__ Hin, float* __restrict__ out, int n) {
  int tid = blockIdx.x * 256 + threadIdx.x;
  int r = tid >> 4;
  int f = tid & 15;
  if (r >= n) return;
  int beg = row_ptr[r], end = row_ptr[r + 1];
  float4 acc = make_float4(0.f, 0.f, 0.f, 0.f);
#pragma unroll 2
  for (int j = beg; j < end; ++j) {
    int2 ev = sedge[j];
    float v = __int_as_float(ev.y);
    float4 h = ((const float4*)Hin)[(size_t)ev.x * 16 + f];
    acc.x = fmaf(v, h.x, acc.x);
    acc.y = fmaf(v, h.y, acc.y);
    acc.z = fmaf(v, h.z, acc.z);
    acc.w = fmaf(v, h.w, acc.w);
  }
  ((float4*)out)[(size_t)r * 16 + f] = acc;
}

__global__ __launch_bounds__(256) void spmm128_csr(
    const int* __restrict__ row_ptr, const int2* __restrict__ sedge,
    const float* __restrict__ Hin, float* __restrict__ out, int n) {
  int tid = blockIdx.x * 256 + threadIdx.x;
  int r = tid >> 5;
  int f = tid & 31;
  if (r >= n) return;
  int beg = row_ptr[r], end = row_ptr[r + 1];
  float4 acc = make_float4(0.f, 0.f, 0.f, 0.f);
#pragma unroll 2
  for (int j = beg; j < end; ++j) {
    int2 ev = sedge[j];
    float v = __int_as_float(ev.y);
    float4 h = ((const float4*)Hin)[(size_t)ev.x * 32 + f];
    acc.x = fmaf(v, h.x, acc.x);
    acc.y = fmaf(v, h.y, acc.y);
    acc.z = fmaf(v, h.z, acc.z);
    acc.w = fmaf(v, h.w, acc.w);
  }
  ((float4*)out)[(size_t)r * 32 + f] = acc;
}

// ---------------- fallback atomic SpMM (if ws too small / n too big) --------
__global__ __launch_bounds__(256) void spmm64_atomic(
    const int* __restrict__ row, const int* __restrict__ col,
    const float* __restrict__ vals, const float* __restrict__ Hin,
    float* __restrict__ out, int n_edges) {
  int tid = blockIdx.x * 256 + threadIdx.x;
  int e = tid >> 4, f = tid & 15;
  if (e >= n_edges) return;
  int c = col[e], r = row[e];
  float v = vals[e];
  float4 h = ((const float4*)Hin)[(size_t)c * 16 + f];
  float* o = out + (size_t)r * 64 + f * 4;
  atomicAdd(o + 0, v * h.x);
  atomicAdd(o + 1, v * h.y);
  atomicAdd(o + 2, v * h.z);
  atomicAdd(o + 3, v * h.w);
}

__global__ __launch_bounds__(256) void spmm128_atomic(
    const int* __restrict__ row, const int* __restrict__ col,
    const float* __restrict__ vals, const float* __restrict__ Hin,
    float* __restrict__ out, int n_edges) {
  int tid = blockIdx.x * 256 + threadIdx.x;
  int e = tid >> 5, f = tid & 31;
  if (e >= n_edges) return;
  int c = col[e], r = row[e];
  float v = vals[e];
  float4 h = ((const float4*)Hin)[(size_t)c * 32 + f];
  float* o = out + (size_t)r * 128 + f * 4;
  atomicAdd(o + 0, v * h.x);
  atomicAdd(o + 1, v * h.y);
  atomicAdd(o + 2, v * h.z);
  atomicAdd(o + 3, v * h.w);
}

// ---------------- register-tiled f32 GEMM + bias + relu ----------------
template <int K>
__global__ __launch_bounds__(256) void gemm_tiled_relu(
    const float* __restrict__ A, const float* __restrict__ W,
    const float* __restrict__ b, float* __restrict__ out, int n) {
  constexpr int KB = 32;
  constexpr int RP = 132;
  __shared__ float As[KB][RP];
  __shared__ float Ws[KB][128];
  const int t = threadIdx.x;
  const int tx = t & 15, ty = t >> 4;
  const int r0 = blockIdx.x * 128;

  float4 acc0[8], acc1[8];
#pragma unroll
  for (int i = 0; i < 8; ++i) {
    acc0[i] = make_float4(0.f, 0.f, 0.f, 0.f);
    acc1[i] = make_float4(0.f, 0.f, 0.f, 0.f);
  }

  for (int k0 = 0; k0 < K; k0 += KB) {
#pragma unroll
    for (int q = 0; q < 4; ++q) {
      int f = q * 256 + t;
      int kk = f >> 5, cv = f & 31;
      ((float4*)&Ws[kk][0])[cv] =
          ((const float4*)(W + (size_t)(k0 + kk) * 128))[cv];
    }
#pragma unroll
    for (int q = 0; q < 4; ++q) {
      int f = q * 256 + t;
      int r = f >> 3, kv = f & 7;
      float4 av = make_float4(0.f, 0.f, 0.f, 0.f);
      if (r0 + r < n) av = ((const float4*)(A + (size_t)(r0 + r) * K + k0))[kv];
      As[4 * kv + 0][r] = av.x;
      As[4 * kv + 1][r] = av.y;
      As[4 * kv + 2][r] = av.z;
      As[4 * kv + 3][r] = av.w;
    }
    __syncthreads();
#pragma unroll
    for (int k = 0; k < KB; ++k) {
      float4 w0 = *((const float4*)&Ws[k][4 * tx]);
      float4 w1 = *((const float4*)&Ws[k][64 + 4 * tx]);
#pragma unroll
      for (int i = 0; i < 8; ++i) {
        float a = As[k][ty + 16 * i];
        acc0[i].x = fmaf(a, w0.x, acc0[i].x);
        acc0[i].y = fmaf(a, w0.y, acc0[i].y);
        acc0[i].z = fmaf(a, w0.z, acc0[i].z);
        acc0[i].w = fmaf(a, w0.w, acc0[i].w);
        acc1[i].x = fmaf(a, w1.x, acc1[i].x);
        acc1[i].y = fmaf(a, w1.y, acc1[i].y);
        acc1[i].z = fmaf(a, w1.z, acc1[i].z);
        acc1[i].w = fmaf(a, w1.w, acc1[i].w);
      }
    }
    __syncthreads();
  }

  float4 bb0 = ((const float4*)b)[tx];
  float4 bb1 = ((const float4*)(b + 64))[tx];
#pragma unroll
  for (int i = 0; i < 8; ++i) {
    int r = r0 + ty + 16 * i;
    if (r >= n) continue;
    float4 o0, o1;
    o0.x = fmaxf(acc0[i].x + bb0.x, 0.f);
    o0.y = fmaxf(acc0[i].y + bb0.y, 0.f);
    o0.z = fmaxf(acc0[i].z + bb0.z, 0.f);
    o0.w = fmaxf(acc0[i].w + bb0.w, 0.f);
    o1.x = fmaxf(acc1[i].x + bb1.x, 0.f);
    o1.y = fmaxf(acc1[i].y + bb1.y, 0.f);
    o1.z = fmaxf(acc1[i].z + bb1.z, 0.f);
    o1.w = fmaxf(acc1[i].w + bb1.w, 0.f);
    ((float4*)(out + (size_t)r * 128))[tx] = o0;
    ((float4*)(out + (size_t)r * 128 + 64))[tx] = o1;
  }
}

extern "C" void kernel_launch(void* const* d_in, const int* in_sizes, int n_in,
                              void* d_out, int out_size, void* d_ws, size_t ws_size,
                              hipStream_t stream) {
  const int* row = (const int*)d_in[0];
  const int* col = (const int*)d_in[1];
  const float* vals = (const float*)d_in[2];
  const float* H = (const float*)d_in[3];
  const float* W1 = (const float*)d_in[4];
  const float* b1 = (const float*)d_in[5];
  const float* W2 = (const float*)d_in[6];
  const float* b2 = (const float*)d_in[7];
  float* out = (float*)d_out;

  const int n_edges = in_sizes[0];
  const int n_nodes = in_sizes[3] / NFEAT;
  const int nb = (n_nodes + BROWS - 1) / BROWS;
  const int gemm_grid = (n_nodes + 127) / 128;

  // Workspace layout:
  // AH (N*64 f32, doubles as bedge scratch: E int2 <= N*64 f32 here)
  // | H1 (N*128) | sedge (E int2) | bcnt (NB_MAX) | bbase (NB_MAX+1)
  // | cur (NB_MAX) | row_ptr (N+1)
  size_t off = 0;
  float* AH = (float*)((char*)d_ws + off);
  size_t ah_bytes = (size_t)n_nodes * NFEAT * 4;
  size_t bedge_bytes = (size_t)n_edges * 8;
  off += (ah_bytes > bedge_bytes ? ah_bytes : bedge_bytes);
  float* H1 = (float*)((char*)d_ws + off);   off += (size_t)n_nodes * NHID * 4;
  int2* sedge = (int2*)((char*)d_ws + off);  off += (size_t)n_edges * 8;
  int* bcnt = (int*)((char*)d_ws + off);     off += NB_MAX * 4;
  int* bbase = (int*)((char*)d_ws + off);    off += (NB_MAX + 1) * 4;
  int* cur = (int*)((char*)d_ws + off);      off += NB_MAX * 4;
  int* row_ptr = (int*)((char*)d_ws + off);  off += ((size_t)n_nodes + 1) * 4;
  const size_t needed = off;
  int2* bedge = (int2*)AH;  // consumed by bucket_csr before spmm64 writes AH

  if (ws_size >= needed && nb <= NB_MAX && n_nodes <= (1 << 17)) {
    // ---- bucket-sort CSR path ----
    hipMemsetAsync(bcnt, 0, NB_MAX * sizeof(int), stream);
    bhist_kernel<<<256, 256, 0, stream>>>(row, bcnt, n_edges, nb);
    bscan_kernel<<<1, NB_MAX, 0, stream>>>(bcnt, bbase, cur, row_ptr, nb, n_nodes);
    partition_kernel<<<256, 256, 0, stream>>>(row, col, vals, cur, bedge, n_edges);
    bucket_csr_kernel<<<nb, 512, 0, stream>>>(bbase, bedge, row_ptr, sedge, n_nodes);

    // Layer 1
    spmm64_csr<<<(n_nodes * 16 + 255) / 256, 256, 0, stream>>>(row_ptr, sedge, H, AH, n_nodes);
    gemm_tiled_relu<64><<<gemm_grid, 256, 0, stream>>>(AH, W1, b1, H1, n_nodes);
    // Layer 2 (AH1 in d_out, gemm in-place)
    spmm128_csr<<<(n_nodes * 32 + 255) / 256, 256, 0, stream>>>(row_ptr, sedge, H1, out, n_nodes);
    gemm_tiled_relu<128><<<gemm_grid, 256, 0, stream>>>(out, W2, b2, out, n_nodes);
  } else {
    // ---- fallback: atomic scatter path ----
    float* fAH = (float*)d_ws;
    float* fH1 = fAH + (size_t)n_nodes * NFEAT;
    hipMemsetAsync(fAH, 0, (size_t)n_nodes * NFEAT * sizeof(float), stream);
    hipMemsetAsync(out, 0, (size_t)n_nodes * NHID * sizeof(float), stream);
    spmm64_atomic<<<(n_edges * 16 + 255) / 256, 256, 0, stream>>>(row, col, vals, H, fAH, n_edges);
    gemm_tiled_relu<64><<<gemm_grid, 256, 0, stream>>>(fAH, W1, b1, fH1, n_nodes);
    spmm128_atomic<<<(n_edges * 32 + 255) / 256, 256, 0, stream>>>(row, col, vals, fH1, out, n_edges);
    gemm_tiled_relu<128><<<gemm_grid, 256, 0, stream>>>(out, W2, b2, out, n_nodes);
  }
}

// Round 6
// 470.048 us; speedup vs baseline: 9.6748x; 1.0007x over previous
//
#include <hip/hip_runtime.h>

// GCN: H2 = relu(A @ relu(A@H @ W1 + b1) @ W2 + b2)
// A: COO (row,col,vals), E=1.6M, N=100k, feats 64 -> 128 -> 128.
// R6: SpMM inner loop restructured into branch-free chunks of 8 with clamped
// tail (MLP fix: 8 independent gathers in flight per row-group, was ~1).

#define NFEAT 64
#define NHID 128
#define BSHIFT 9              // 512 rows per bucket
#define BROWS (1 << BSHIFT)
#define NB_MAX 256            // supports n_nodes <= 131072 (also 17-bit col pack)

// ---------------- bucket histogram (LDS-aggregated) ----------------
__global__ __launch_bounds__(256) void bhist_kernel(
    const int* __restrict__ row, int* __restrict__ bcnt, int n_edges, int nb) {
  __shared__ int h[NB_MAX];
  for (int i = threadIdx.x; i < NB_MAX; i += 256) h[i] = 0;
  __syncthreads();
  for (int e = blockIdx.x * 256 + threadIdx.x; e < n_edges; e += gridDim.x * 256)
    atomicAdd(&h[row[e] >> BSHIFT], 1);
  __syncthreads();
  for (int i = threadIdx.x; i < nb; i += 256)
    if (h[i]) atomicAdd(&bcnt[i], h[i]);
}

// ---------------- bucket scan -> bbase[nb+1], cur[nb], row_ptr[n] -----------
__global__ __launch_bounds__(NB_MAX) void bscan_kernel(
    const int* __restrict__ bcnt, int* __restrict__ bbase, int* __restrict__ cur,
    int* __restrict__ row_ptr, int nb, int n) {
  __shared__ int sm[NB_MAX];
  int t = threadIdx.x;
  int v = (t < nb) ? bcnt[t] : 0;
  sm[t] = v;
  __syncthreads();
  for (int off = 1; off < NB_MAX; off <<= 1) {
    int u = (t >= off) ? sm[t - off] : 0;
    __syncthreads();
    sm[t] += u;
    __syncthreads();
  }
  if (t < nb) {
    bbase[t] = sm[t] - v;
    cur[t] = sm[t] - v;
  }
  if (t == nb - 1) {
    bbase[nb] = sm[t];
    row_ptr[n] = sm[t];
  }
}

// ---------------- pass A: multi-split partition into buckets ----------------
__global__ __launch_bounds__(256) void partition_kernel(
    const int* __restrict__ row, const int* __restrict__ col,
    const float* __restrict__ vals, int* __restrict__ cur,
    int2* __restrict__ bedge, int n_edges) {
  __shared__ int h[NB_MAX], base[NB_MAX], rk[NB_MAX];
  for (int i = threadIdx.x; i < NB_MAX; i += 256) {
    h[i] = 0;
    rk[i] = 0;
  }
  __syncthreads();
  const int start = blockIdx.x * 256 + threadIdx.x;
  const int step = gridDim.x * 256;
  for (int e = start; e < n_edges; e += step)
    atomicAdd(&h[row[e] >> BSHIFT], 1);
  __syncthreads();
  for (int i = threadIdx.x; i < NB_MAX; i += 256)
    base[i] = h[i] ? atomicAdd(&cur[i], h[i]) : 0;
  __syncthreads();
  for (int e = start; e < n_edges; e += step) {
    int r = row[e];
    int b = r >> BSHIFT;
    int rl = r & (BROWS - 1);
    int p = base[b] + atomicAdd(&rk[b], 1);
    bedge[p] = make_int2((rl << 17) | col[e], __float_as_int(vals[e]));
  }
}

// ---------------- pass B: per-bucket exact CSR ----------------
__global__ __launch_bounds__(512) void bucket_csr_kernel(
    const int* __restrict__ bbase, const int2* __restrict__ bedge,
    int* __restrict__ row_ptr, int2* __restrict__ sedge, int n) {
  __shared__ int cnt[BROWS];
  __shared__ int sm[BROWS];
  const int b = blockIdx.x;
  const int t = threadIdx.x;
  const int beg = bbase[b], end = bbase[b + 1];
  cnt[t] = 0;
  __syncthreads();
  for (int j = beg + t; j < end; j += 512)
    atomicAdd(&cnt[((unsigned)bedge[j].x) >> 17], 1);
  __syncthreads();
  int v = cnt[t];
  sm[t] = v;
  __syncthreads();
  for (int off = 1; off < BROWS; off <<= 1) {
    int u = (t >= off) ? sm[t - off] : 0;
    __syncthreads();
    sm[t] += u;
    __syncthreads();
  }
  {
    int incl = sm[t];
    __syncthreads();
    sm[t] = incl - v;  // exclusive local base
  }
  int r = (b << BSHIFT) + t;
  if (r < n) row_ptr[r] = beg + sm[t];
  cnt[t] = 0;
  __syncthreads();
  for (int j = beg + t; j < end; j += 512) {
    int2 ev = bedge[j];
    int rl = ((unsigned)ev.x) >> 17;
    int rank = atomicAdd(&cnt[rl], 1);
    sedge[beg + sm[rl] + rank] = make_int2(ev.x & 0x1FFFF, ev.y);
  }
}

// ---------------- CSR gather SpMM (MLP-restructured) ----------------
// 64 feats: 16 lanes per row, one float4 per lane. Edge loop in branch-free
// chunks of 8: clamped idx duplicates the last edge (same line -> cache hit),
// tail terms multiplied by 0 -> bit-identical result, 8 gathers in flight.
__global__ __launch_bounds__(256) void spmm64_csr(
    const int* __restrict__ row_ptr, const int2* __restrict__ sedge,
    const float* __restrict__ Hin, float* __restrict__ out, int n) {
  int tid = blockIdx.x * 256 + threadIdx.x;
  int r = tid >> 4;
  int f = tid & 15;
  if (r >= n) return;
  int beg = row_ptr[r], end = row_ptr[r + 1];
  int end1 = end - 1;
  float4 acc = make_float4(0.f, 0.f, 0.f, 0.f);
  for (int c0 = beg; c0 < end; c0 += 8) {
#pragma unroll
    for (int j = 0; j < 8; ++j) {
      int idx = min(c0 + j, end1);
      int2 ev = sedge[idx];
      float v = (c0 + j < end) ? __int_as_float(ev.y) : 0.f;
      float4 h = ((const float4*)Hin)[(size_t)ev.x * 16 + f];
      acc.x = fmaf(v, h.x, acc.x);
      acc.y = fmaf(v, h.y, acc.y);
      acc.z = fmaf(v, h.z, acc.z);
      acc.w = fmaf(v, h.w, acc.w);
    }
  }
  ((float4*)out)[(size_t)r * 16 + f] = acc;
}

// 128 feats: 32 lanes per row.
__global__ __launch_bounds__(256) void spmm128_csr(
    const int* __restrict__ row_ptr, const int2* __restrict__ sedge,
    const float* __restrict__ Hin, float* __restrict__ out, int n) {
  int tid = blockIdx.x * 256 + threadIdx.x;
  int r = tid >> 5;
  int f = tid & 31;
  if (r >= n) return;
  int beg = row_ptr[r], end = row_ptr[r + 1];
  int end1 = end - 1;
  float4 acc = make_float4(0.f, 0.f, 0.f, 0.f);
  for (int c0 = beg; c0 < end; c0 += 8) {
#pragma unroll
    for (int j = 0; j < 8; ++j) {
      int idx = min(c0 + j, end1);
      int2 ev = sedge[idx];
      float v = (c0 + j < end) ? __int_as_float(ev.y) : 0.f;
      float4 h = ((const float4*)Hin)[(size_t)ev.x * 32 + f];
      acc.x = fmaf(v, h.x, acc.x);
      acc.y = fmaf(v, h.y, acc.y);
      acc.z = fmaf(v, h.z, acc.z);
      acc.w = fmaf(v, h.w, acc.w);
    }
  }
  ((float4*)out)[(size_t)r * 32 + f] = acc;
}

// ---------------- fallback atomic SpMM (if ws too small / n too big) --------
__global__ __launch_bounds__(256) void spmm64_atomic(
    const int* __restrict__ row, const int* __restrict__ col,
    const float* __restrict__ vals, const float* __restrict__ Hin,
    float* __restrict__ out, int n_edges) {
  int tid = blockIdx.x * 256 + threadIdx.x;
  int e = tid >> 4, f = tid & 15;
  if (e >= n_edges) return;
  int c = col[e], r = row[e];
  float v = vals[e];
  float4 h = ((const float4*)Hin)[(size_t)c * 16 + f];
  float* o = out + (size_t)r * 64 + f * 4;
  atomicAdd(o + 0, v * h.x);
  atomicAdd(o + 1, v * h.y);
  atomicAdd(o + 2, v * h.z);
  atomicAdd(o + 3, v * h.w);
}

__global__ __launch_bounds__(256) void spmm128_atomic(
    const int* __restrict__ row, const int* __restrict__ col,
    const float* __restrict__ vals, const float* __restrict__ Hin,
    float* __restrict__ out, int n_edges) {
  int tid = blockIdx.x * 256 + threadIdx.x;
  int e = tid >> 5, f = tid & 31;
  if (e >= n_edges) return;
  int c = col[e], r = row[e];
  float v = vals[e];
  float4 h = ((const float4*)Hin)[(size_t)c * 32 + f];
  float* o = out + (size_t)r * 128 + f * 4;
  atomicAdd(o + 0, v * h.x);
  atomicAdd(o + 1, v * h.y);
  atomicAdd(o + 2, v * h.z);
  atomicAdd(o + 3, v * h.w);
}

// ---------------- register-tiled f32 GEMM + bias + relu ----------------
template <int K>
__global__ __launch_bounds__(256) void gemm_tiled_relu(
    const float* __restrict__ A, const float* __restrict__ W,
    const float* __restrict__ b, float* __restrict__ out, int n) {
  constexpr int KB = 32;
  constexpr int RP = 132;
  __shared__ float As[KB][RP];
  __shared__ float Ws[KB][128];
  const int t = threadIdx.x;
  const int tx = t & 15, ty = t >> 4;
  const int r0 = blockIdx.x * 128;

  float4 acc0[8], acc1[8];
#pragma unroll
  for (int i = 0; i < 8; ++i) {
    acc0[i] = make_float4(0.f, 0.f, 0.f, 0.f);
    acc1[i] = make_float4(0.f, 0.f, 0.f, 0.f);
  }

  for (int k0 = 0; k0 < K; k0 += KB) {
#pragma unroll
    for (int q = 0; q < 4; ++q) {
      int f = q * 256 + t;
      int kk = f >> 5, cv = f & 31;
      ((float4*)&Ws[kk][0])[cv] =
          ((const float4*)(W + (size_t)(k0 + kk) * 128))[cv];
    }
#pragma unroll
    for (int q = 0; q < 4; ++q) {
      int f = q * 256 + t;
      int r = f >> 3, kv = f & 7;
      float4 av = make_float4(0.f, 0.f, 0.f, 0.f);
      if (r0 + r < n) av = ((const float4*)(A + (size_t)(r0 + r) * K + k0))[kv];
      As[4 * kv + 0][r] = av.x;
      As[4 * kv + 1][r] = av.y;
      As[4 * kv + 2][r] = av.z;
      As[4 * kv + 3][r] = av.w;
    }
    __syncthreads();
#pragma unroll
    for (int k = 0; k < KB; ++k) {
      float4 w0 = *((const float4*)&Ws[k][4 * tx]);
      float4 w1 = *((const float4*)&Ws[k][64 + 4 * tx]);
#pragma unroll
      for (int i = 0; i < 8; ++i) {
        float a = As[k][ty + 16 * i];
        acc0[i].x = fmaf(a, w0.x, acc0[i].x);
        acc0[i].y = fmaf(a, w0.y, acc0[i].y);
        acc0[i].z = fmaf(a, w0.z, acc0[i].z);
        acc0[i].w = fmaf(a, w0.w, acc0[i].w);
        acc1[i].x = fmaf(a, w1.x, acc1[i].x);
        acc1[i].y = fmaf(a, w1.y, acc1[i].y);
        acc1[i].z = fmaf(a, w1.z, acc1[i].z);
        acc1[i].w = fmaf(a, w1.w, acc1[i].w);
      }
    }
    __syncthreads();
  }

  float4 bb0 = ((const float4*)b)[tx];
  float4 bb1 = ((const float4*)(b + 64))[tx];
#pragma unroll
  for (int i = 0; i < 8; ++i) {
    int r = r0 + ty + 16 * i;
    if (r >= n) continue;
    float4 o0, o1;
    o0.x = fmaxf(acc0[i].x + bb0.x, 0.f);
    o0.y = fmaxf(acc0[i].y + bb0.y, 0.f);
    o0.z = fmaxf(acc0[i].z + bb0.z, 0.f);
    o0.w = fmaxf(acc0[i].w + bb0.w, 0.f);
    o1.x = fmaxf(acc1[i].x + bb1.x, 0.f);
    o1.y = fmaxf(acc1[i].y + bb1.y, 0.f);
    o1.z = fmaxf(acc1[i].z + bb1.z, 0.f);
    o1.w = fmaxf(acc1[i].w + bb1.w, 0.f);
    ((float4*)(out + (size_t)r * 128))[tx] = o0;
    ((float4*)(out + (size_t)r * 128 + 64))[tx] = o1;
  }
}

extern "C" void kernel_launch(void* const* d_in, const int* in_sizes, int n_in,
                              void* d_out, int out_size, void* d_ws, size_t ws_size,
                              hipStream_t stream) {
  const int* row = (const int*)d_in[0];
  const int* col = (const int*)d_in[1];
  const float* vals = (const float*)d_in[2];
  const float* H = (const float*)d_in[3];
  const float* W1 = (const float*)d_in[4];
  const float* b1 = (const float*)d_in[5];
  const float* W2 = (const float*)d_in[6];
  const float* b2 = (const float*)d_in[7];
  float* out = (float*)d_out;

  const int n_edges = in_sizes[0];
  const int n_nodes = in_sizes[3] / NFEAT;
  const int nb = (n_nodes + BROWS - 1) / BROWS;
  const int gemm_grid = (n_nodes + 127) / 128;

  // Workspace layout:
  // AH (N*64 f32, doubles as bedge scratch) | H1 (N*128) | sedge (E int2)
  // | bcnt (NB_MAX) | bbase (NB_MAX+1) | cur (NB_MAX) | row_ptr (N+1)
  size_t off = 0;
  float* AH = (float*)((char*)d_ws + off);
  size_t ah_bytes = (size_t)n_nodes * NFEAT * 4;
  size_t bedge_bytes = (size_t)n_edges * 8;
  off += (ah_bytes > bedge_bytes ? ah_bytes : bedge_bytes);
  float* H1 = (float*)((char*)d_ws + off);   off += (size_t)n_nodes * NHID * 4;
  int2* sedge = (int2*)((char*)d_ws + off);  off += (size_t)n_edges * 8;
  int* bcnt = (int*)((char*)d_ws + off);     off += NB_MAX * 4;
  int* bbase = (int*)((char*)d_ws + off);    off += (NB_MAX + 1) * 4;
  int* cur = (int*)((char*)d_ws + off);      off += NB_MAX * 4;
  int* row_ptr = (int*)((char*)d_ws + off);  off += ((size_t)n_nodes + 1) * 4;
  const size_t needed = off;
  int2* bedge = (int2*)AH;  // consumed by bucket_csr before spmm64 writes AH

  if (ws_size >= needed && nb <= NB_MAX && n_nodes <= (1 << 17)) {
    // ---- bucket-sort CSR path ----
    hipMemsetAsync(bcnt, 0, NB_MAX * sizeof(int), stream);
    bhist_kernel<<<256, 256, 0, stream>>>(row, bcnt, n_edges, nb);
    bscan_kernel<<<1, NB_MAX, 0, stream>>>(bcnt, bbase, cur, row_ptr, nb, n_nodes);
    partition_kernel<<<256, 256, 0, stream>>>(row, col, vals, cur, bedge, n_edges);
    bucket_csr_kernel<<<nb, 512, 0, stream>>>(bbase, bedge, row_ptr, sedge, n_nodes);

    // Layer 1
    spmm64_csr<<<(n_nodes * 16 + 255) / 256, 256, 0, stream>>>(row_ptr, sedge, H, AH, n_nodes);
    gemm_tiled_relu<64><<<gemm_grid, 256, 0, stream>>>(AH, W1, b1, H1, n_nodes);
    // Layer 2 (AH1 in d_out, gemm in-place)
    spmm128_csr<<<(n_nodes * 32 + 255) / 256, 256, 0, stream>>>(row_ptr, sedge, H1, out, n_nodes);
    gemm_tiled_relu<128><<<gemm_grid, 256, 0, stream>>>(out, W2, b2, out, n_nodes);
  } else {
    // ---- fallback: atomic scatter path ----
    float* fAH = (float*)d_ws;
    float* fH1 = fAH + (size_t)n_nodes * NFEAT;
    hipMemsetAsync(fAH, 0, (size_t)n_nodes * NFEAT * sizeof(float), stream);
    hipMemsetAsync(out, 0, (size_t)n_nodes * NHID * sizeof(float), stream);
    spmm64_atomic<<<(n_edges * 16 + 255) / 256, 256, 0, stream>>>(row, col, vals, H, fAH, n_edges);
    gemm_tiled_relu<64><<<gemm_grid, 256, 0, stream>>>(fAH, W1, b1, fH1, n_nodes);
    spmm128_atomic<<<(n_edges * 32 + 255) / 256, 256, 0, stream>>>(row, col, vals, fH1, out, n_edges);
    gemm_tiled_relu<128><<<gemm_grid, 256, 0, stream>>>(out, W2, b2, out, n_nodes);
  }
}

// Round 7
// 400.657 us; speedup vs baseline: 11.3503x; 1.1732x over previous
//
#include <hip/hip_runtime.h>

// GCN: H2 = relu(A @ relu(A@H @ W1 + b1) @ W2 + b2)
// A: COO (row,col,vals), E=1.6M, N=100k, feats 64 -> 128 -> 128.
// R7: bf16 storage for gathered operands (H, H1) -> halves SpMM gather bytes.
// SpMM accumulates f32; sedge vals stay f32. R6's clamped-unroll reverted
// (neutral: MLP was already covered by TLP at 76% occupancy).

#define NFEAT 64
#define NHID 128
#define BSHIFT 9              // 512 rows per bucket
#define BROWS (1 << BSHIFT)
#define NB_MAX 256            // supports n_nodes <= 131072 (17-bit col pack)

// ---------------- bf16 helpers ----------------
__device__ __forceinline__ unsigned short f2bf(float x) {
  unsigned u = __float_as_uint(x);
  unsigned r = (u + 0x7FFFu + ((u >> 16) & 1u)) >> 16;  // RNE
  return (unsigned short)r;
}
__device__ __forceinline__ float bf_lo(unsigned w) {
  return __uint_as_float(w << 16);
}
__device__ __forceinline__ float bf_hi(unsigned w) {
  return __uint_as_float(w & 0xFFFF0000u);
}

// f32 -> bf16 pack, 4 elems/thread.
__global__ __launch_bounds__(256) void tobf16_kernel(
    const float* __restrict__ src, unsigned short* __restrict__ dst, int n4) {
  for (int i = blockIdx.x * 256 + threadIdx.x; i < n4; i += gridDim.x * 256) {
    float4 a = ((const float4*)src)[i];
    unsigned lo = (unsigned)f2bf(a.x) | ((unsigned)f2bf(a.y) << 16);
    unsigned hi = (unsigned)f2bf(a.z) | ((unsigned)f2bf(a.w) << 16);
    ((uint2*)dst)[i] = make_uint2(lo, hi);
  }
}

// ---------------- bucket histogram (LDS-aggregated) ----------------
__global__ __launch_bounds__(256) void bhist_kernel(
    const int* __restrict__ row, int* __restrict__ bcnt, int n_edges, int nb) {
  __shared__ int h[NB_MAX];
  for (int i = threadIdx.x; i < NB_MAX; i += 256) h[i] = 0;
  __syncthreads();
  for (int e = blockIdx.x * 256 + threadIdx.x; e < n_edges; e += gridDim.x * 256)
    atomicAdd(&h[row[e] >> BSHIFT], 1);
  __syncthreads();
  for (int i = threadIdx.x; i < nb; i += 256)
    if (h[i]) atomicAdd(&bcnt[i], h[i]);
}

// ---------------- bucket scan -> bbase[nb+1], cur[nb], row_ptr[n] -----------
__global__ __launch_bounds__(NB_MAX) void bscan_kernel(
    const int* __restrict__ bcnt, int* __restrict__ bbase, int* __restrict__ cur,
    int* __restrict__ row_ptr, int nb, int n) {
  __shared__ int sm[NB_MAX];
  int t = threadIdx.x;
  int v = (t < nb) ? bcnt[t] : 0;
  sm[t] = v;
  __syncthreads();
  for (int off = 1; off < NB_MAX; off <<= 1) {
    int u = (t >= off) ? sm[t - off] : 0;
    __syncthreads();
    sm[t] += u;
    __syncthreads();
  }
  if (t < nb) {
    bbase[t] = sm[t] - v;
    cur[t] = sm[t] - v;
  }
  if (t == nb - 1) {
    bbase[nb] = sm[t];
    row_ptr[n] = sm[t];
  }
}

// ---------------- pass A: multi-split partition into buckets ----------------
__global__ __launch_bounds__(256) void partition_kernel(
    const int* __restrict__ row, const int* __restrict__ col,
    const float* __restrict__ vals, int* __restrict__ cur,
    int2* __restrict__ bedge, int n_edges) {
  __shared__ int h[NB_MAX], base[NB_MAX], rk[NB_MAX];
  for (int i = threadIdx.x; i < NB_MAX; i += 256) {
    h[i] = 0;
    rk[i] = 0;
  }
  __syncthreads();
  const int start = blockIdx.x * 256 + threadIdx.x;
  const int step = gridDim.x * 256;
  for (int e = start; e < n_edges; e += step)
    atomicAdd(&h[row[e] >> BSHIFT], 1);
  __syncthreads();
  for (int i = threadIdx.x; i < NB_MAX; i += 256)
    base[i] = h[i] ? atomicAdd(&cur[i], h[i]) : 0;
  __syncthreads();
  for (int e = start; e < n_edges; e += step) {
    int r = row[e];
    int b = r >> BSHIFT;
    int rl = r & (BROWS - 1);
    int p = base[b] + atomicAdd(&rk[b], 1);
    bedge[p] = make_int2((rl << 17) | col[e], __float_as_int(vals[e]));
  }
}

// ---------------- pass B: per-bucket exact CSR ----------------
__global__ __launch_bounds__(512) void bucket_csr_kernel(
    const int* __restrict__ bbase, const int2* __restrict__ bedge,
    int* __restrict__ row_ptr, int2* __restrict__ sedge, int n) {
  __shared__ int cnt[BROWS];
  __shared__ int sm[BROWS];
  const int b = blockIdx.x;
  const int t = threadIdx.x;
  const int beg = bbase[b], end = bbase[b + 1];
  cnt[t] = 0;
  __syncthreads();
  for (int j = beg + t; j < end; j += 512)
    atomicAdd(&cnt[((unsigned)bedge[j].x) >> 17], 1);
  __syncthreads();
  int v = cnt[t];
  sm[t] = v;
  __syncthreads();
  for (int off = 1; off < BROWS; off <<= 1) {
    int u = (t >= off) ? sm[t - off] : 0;
    __syncthreads();
    sm[t] += u;
    __syncthreads();
  }
  {
    int incl = sm[t];
    __syncthreads();
    sm[t] = incl - v;  // exclusive local base
  }
  int r = (b << BSHIFT) + t;
  if (r < n) row_ptr[r] = beg + sm[t];
  cnt[t] = 0;
  __syncthreads();
  for (int j = beg + t; j < end; j += 512) {
    int2 ev = bedge[j];
    int rl = ((unsigned)ev.x) >> 17;
    int rank = atomicAdd(&cnt[rl], 1);
    sedge[beg + sm[rl] + rank] = make_int2(ev.x & 0x1FFFF, ev.y);
  }
}

// ---------------- CSR gather SpMM, bf16 operand ----------------
// 64 feats bf16 = 128 B/row: 8 lanes per row, one uint4 (8 bf16) per lane.
__global__ __launch_bounds__(256) void spmm64_csr_bf(
    const int* __restrict__ row_ptr, const int2* __restrict__ sedge,
    const unsigned short* __restrict__ Hbf, float* __restrict__ out, int n) {
  int tid = blockIdx.x * 256 + threadIdx.x;
  int r = tid >> 3;
  int f = tid & 7;
  if (r >= n) return;
  const uint4* Hq = (const uint4*)Hbf;  // 8 uint4 per 64-feat row
  int beg = row_ptr[r], end = row_ptr[r + 1];
  float acc[8] = {0.f, 0.f, 0.f, 0.f, 0.f, 0.f, 0.f, 0.f};
#pragma unroll 2
  for (int j = beg; j < end; ++j) {
    int2 ev = sedge[j];
    float v = __int_as_float(ev.y);
    uint4 q = Hq[(size_t)ev.x * 8 + f];
    acc[0] = fmaf(v, bf_lo(q.x), acc[0]);
    acc[1] = fmaf(v, bf_hi(q.x), acc[1]);
    acc[2] = fmaf(v, bf_lo(q.y), acc[2]);
    acc[3] = fmaf(v, bf_hi(q.y), acc[3]);
    acc[4] = fmaf(v, bf_lo(q.z), acc[4]);
    acc[5] = fmaf(v, bf_hi(q.z), acc[5]);
    acc[6] = fmaf(v, bf_lo(q.w), acc[6]);
    acc[7] = fmaf(v, bf_hi(q.w), acc[7]);
  }
  float* o = out + (size_t)r * 64 + f * 8;
  ((float4*)o)[0] = make_float4(acc[0], acc[1], acc[2], acc[3]);
  ((float4*)o)[1] = make_float4(acc[4], acc[5], acc[6], acc[7]);
}

// 128 feats bf16 = 256 B/row: 16 lanes per row.
__global__ __launch_bounds__(256) void spmm128_csr_bf(
    const int* __restrict__ row_ptr, const int2* __restrict__ sedge,
    const unsigned short* __restrict__ Hbf, float* __restrict__ out, int n) {
  int tid = blockIdx.x * 256 + threadIdx.x;
  int r = tid >> 4;
  int f = tid & 15;
  if (r >= n) return;
  const uint4* Hq = (const uint4*)Hbf;  // 16 uint4 per 128-feat row
  int beg = row_ptr[r], end = row_ptr[r + 1];
  float acc[8] = {0.f, 0.f, 0.f, 0.f, 0.f, 0.f, 0.f, 0.f};
#pragma unroll 2
  for (int j = beg; j < end; ++j) {
    int2 ev = sedge[j];
    float v = __int_as_float(ev.y);
    uint4 q = Hq[(size_t)ev.x * 16 + f];
    acc[0] = fmaf(v, bf_lo(q.x), acc[0]);
    acc[1] = fmaf(v, bf_hi(q.x), acc[1]);
    acc[2] = fmaf(v, bf_lo(q.y), acc[2]);
    acc[3] = fmaf(v, bf_hi(q.y), acc[3]);
    acc[4] = fmaf(v, bf_lo(q.z), acc[4]);
    acc[5] = fmaf(v, bf_hi(q.z), acc[5]);
    acc[6] = fmaf(v, bf_lo(q.w), acc[6]);
    acc[7] = fmaf(v, bf_hi(q.w), acc[7]);
  }
  float* o = out + (size_t)r * 128 + f * 8;
  ((float4*)o)[0] = make_float4(acc[0], acc[1], acc[2], acc[3]);
  ((float4*)o)[1] = make_float4(acc[4], acc[5], acc[6], acc[7]);
}

// ---------------- fallback atomic SpMM (f32, if ws too small / n too big) ---
__global__ __launch_bounds__(256) void spmm64_atomic(
    const int* __restrict__ row, const int* __restrict__ col,
    const float* __restrict__ vals, const float* __restrict__ Hin,
    float* __restrict__ out, int n_edges) {
  int tid = blockIdx.x * 256 + threadIdx.x;
  int e = tid >> 4, f = tid & 15;
  if (e >= n_edges) return;
  int c = col[e], r = row[e];
  float v = vals[e];
  float4 h = ((const float4*)Hin)[(size_t)c * 16 + f];
  float* o = out + (size_t)r * 64 + f * 4;
  atomicAdd(o + 0, v * h.x);
  atomicAdd(o + 1, v * h.y);
  atomicAdd(o + 2, v * h.z);
  atomicAdd(o + 3, v * h.w);
}

__global__ __launch_bounds__(256) void spmm128_atomic(
    const int* __restrict__ row, const int* __restrict__ col,
    const float* __restrict__ vals, const float* __restrict__ Hin,
    float* __restrict__ out, int n_edges) {
  int tid = blockIdx.x * 256 + threadIdx.x;
  int e = tid >> 5, f = tid & 31;
  if (e >= n_edges) return;
  int c = col[e], r = row[e];
  float v = vals[e];
  float4 h = ((const float4*)Hin)[(size_t)c * 32 + f];
  float* o = out + (size_t)r * 128 + f * 4;
  atomicAdd(o + 0, v * h.x);
  atomicAdd(o + 1, v * h.y);
  atomicAdd(o + 2, v * h.z);
  atomicAdd(o + 3, v * h.w);
}

// ---------------- register-tiled f32 GEMM + bias + relu ----------------
// BF16OUT: epilogue packs to bf16 (for H1 consumed by spmm128_csr_bf).
template <int K, bool BF16OUT>
__global__ __launch_bounds__(256) void gemm_tiled_relu(
    const float* __restrict__ A, const float* __restrict__ W,
    const float* __restrict__ b, void* __restrict__ out_v, int n) {
  constexpr int KB = 32;
  constexpr int RP = 132;
  __shared__ float As[KB][RP];
  __shared__ float Ws[KB][128];
  const int t = threadIdx.x;
  const int tx = t & 15, ty = t >> 4;
  const int r0 = blockIdx.x * 128;

  float4 acc0[8], acc1[8];
#pragma unroll
  for (int i = 0; i < 8; ++i) {
    acc0[i] = make_float4(0.f, 0.f, 0.f, 0.f);
    acc1[i] = make_float4(0.f, 0.f, 0.f, 0.f);
  }

  for (int k0 = 0; k0 < K; k0 += KB) {
#pragma unroll
    for (int q = 0; q < 4; ++q) {
      int f = q * 256 + t;
      int kk = f >> 5, cv = f & 31;
      ((float4*)&Ws[kk][0])[cv] =
          ((const float4*)(W + (size_t)(k0 + kk) * 128))[cv];
    }
#pragma unroll
    for (int q = 0; q < 4; ++q) {
      int f = q * 256 + t;
      int r = f >> 3, kv = f & 7;
      float4 av = make_float4(0.f, 0.f, 0.f, 0.f);
      if (r0 + r < n) av = ((const float4*)(A + (size_t)(r0 + r) * K + k0))[kv];
      As[4 * kv + 0][r] = av.x;
      As[4 * kv + 1][r] = av.y;
      As[4 * kv + 2][r] = av.z;
      As[4 * kv + 3][r] = av.w;
    }
    __syncthreads();
#pragma unroll
    for (int k = 0; k < KB; ++k) {
      float4 w0 = *((const float4*)&Ws[k][4 * tx]);
      float4 w1 = *((const float4*)&Ws[k][64 + 4 * tx]);
#pragma unroll
      for (int i = 0; i < 8; ++i) {
        float a = As[k][ty + 16 * i];
        acc0[i].x = fmaf(a, w0.x, acc0[i].x);
        acc0[i].y = fmaf(a, w0.y, acc0[i].y);
        acc0[i].z = fmaf(a, w0.z, acc0[i].z);
        acc0[i].w = fmaf(a, w0.w, acc0[i].w);
        acc1[i].x = fmaf(a, w1.x, acc1[i].x);
        acc1[i].y = fmaf(a, w1.y, acc1[i].y);
        acc1[i].z = fmaf(a, w1.z, acc1[i].z);
        acc1[i].w = fmaf(a, w1.w, acc1[i].w);
      }
    }
    __syncthreads();
  }

  float4 bb0 = ((const float4*)b)[tx];
  float4 bb1 = ((const float4*)(b + 64))[tx];
#pragma unroll
  for (int i = 0; i < 8; ++i) {
    int r = r0 + ty + 16 * i;
    if (r >= n) continue;
    float4 o0, o1;
    o0.x = fmaxf(acc0[i].x + bb0.x, 0.f);
    o0.y = fmaxf(acc0[i].y + bb0.y, 0.f);
    o0.z = fmaxf(acc0[i].z + bb0.z, 0.f);
    o0.w = fmaxf(acc0[i].w + bb0.w, 0.f);
    o1.x = fmaxf(acc1[i].x + bb1.x, 0.f);
    o1.y = fmaxf(acc1[i].y + bb1.y, 0.f);
    o1.z = fmaxf(acc1[i].z + bb1.z, 0.f);
    o1.w = fmaxf(acc1[i].w + bb1.w, 0.f);
    if (BF16OUT) {
      unsigned short* ob = (unsigned short*)out_v + (size_t)r * 128;
      uint2 p0 = make_uint2((unsigned)f2bf(o0.x) | ((unsigned)f2bf(o0.y) << 16),
                            (unsigned)f2bf(o0.z) | ((unsigned)f2bf(o0.w) << 16));
      uint2 p1 = make_uint2((unsigned)f2bf(o1.x) | ((unsigned)f2bf(o1.y) << 16),
                            (unsigned)f2bf(o1.z) | ((unsigned)f2bf(o1.w) << 16));
      ((uint2*)ob)[tx] = p0;
      ((uint2*)(ob + 64))[tx] = p1;
    } else {
      float* of = (float*)out_v;
      ((float4*)(of + (size_t)r * 128))[tx] = o0;
      ((float4*)(of + (size_t)r * 128 + 64))[tx] = o1;
    }
  }
}

extern "C" void kernel_launch(void* const* d_in, const int* in_sizes, int n_in,
                              void* d_out, int out_size, void* d_ws, size_t ws_size,
                              hipStream_t stream) {
  const int* row = (const int*)d_in[0];
  const int* col = (const int*)d_in[1];
  const float* vals = (const float*)d_in[2];
  const float* H = (const float*)d_in[3];
  const float* W1 = (const float*)d_in[4];
  const float* b1 = (const float*)d_in[5];
  const float* W2 = (const float*)d_in[6];
  const float* b2 = (const float*)d_in[7];
  float* out = (float*)d_out;

  const int n_edges = in_sizes[0];
  const int n_nodes = in_sizes[3] / NFEAT;
  const int nb = (n_nodes + BROWS - 1) / BROWS;
  const int gemm_grid = (n_nodes + 127) / 128;

  // Workspace layout (CSR path):
  // slab0: max(bedge E*8, AH N*64*4) | H1bf (N*128*2) | Hbf (N*64*2)
  // | sedge (E*8) | bcnt | bbase | cur | row_ptr (N+1)
  size_t off = 0;
  char* base = (char*)d_ws;
  float* AH = (float*)(base + off);
  size_t slab0 = (size_t)n_nodes * NFEAT * 4;
  size_t bedge_bytes = (size_t)n_edges * 8;
  if (bedge_bytes > slab0) slab0 = bedge_bytes;
  off += slab0;
  unsigned short* H1bf = (unsigned short*)(base + off); off += (size_t)n_nodes * NHID * 2;
  unsigned short* Hbf = (unsigned short*)(base + off);  off += (size_t)n_nodes * NFEAT * 2;
  int2* sedge = (int2*)(base + off);  off += (size_t)n_edges * 8;
  int* bcnt = (int*)(base + off);     off += NB_MAX * 4;
  int* bbase = (int*)(base + off);    off += (NB_MAX + 1) * 4;
  int* cur = (int*)(base + off);      off += NB_MAX * 4;
  int* row_ptr = (int*)(base + off);  off += ((size_t)n_nodes + 1) * 4;
  const size_t needed = off;
  int2* bedge = (int2*)AH;  // consumed by bucket_csr before spmm64 writes AH

  if (ws_size >= needed && nb <= NB_MAX && n_nodes <= (1 << 17)) {
    // ---- bucket-sort CSR build ----
    hipMemsetAsync(bcnt, 0, NB_MAX * sizeof(int), stream);
    bhist_kernel<<<256, 256, 0, stream>>>(row, bcnt, n_edges, nb);
    bscan_kernel<<<1, NB_MAX, 0, stream>>>(bcnt, bbase, cur, row_ptr, nb, n_nodes);
    partition_kernel<<<256, 256, 0, stream>>>(row, col, vals, cur, bedge, n_edges);
    bucket_csr_kernel<<<nb, 512, 0, stream>>>(bbase, bedge, row_ptr, sedge, n_nodes);

    // H -> bf16
    tobf16_kernel<<<1024, 256, 0, stream>>>(H, Hbf, n_nodes * NFEAT / 4);

    // Layer 1: AH = A @ Hbf ; H1bf = bf16(relu(AH @ W1 + b1))
    spmm64_csr_bf<<<(n_nodes * 8 + 255) / 256, 256, 0, stream>>>(
        row_ptr, sedge, Hbf, AH, n_nodes);
    gemm_tiled_relu<64, true><<<gemm_grid, 256, 0, stream>>>(AH, W1, b1, H1bf, n_nodes);
    // Layer 2: AH1 (d_out) = A @ H1bf ; H2 = relu(AH1 @ W2 + b2) in-place
    spmm128_csr_bf<<<(n_nodes * 16 + 255) / 256, 256, 0, stream>>>(
        row_ptr, sedge, H1bf, out, n_nodes);
    gemm_tiled_relu<128, false><<<gemm_grid, 256, 0, stream>>>(out, W2, b2, out, n_nodes);
  } else {
    // ---- fallback: atomic scatter path (all f32) ----
    float* fAH = (float*)d_ws;
    float* fH1 = fAH + (size_t)n_nodes * NFEAT;
    hipMemsetAsync(fAH, 0, (size_t)n_nodes * NFEAT * sizeof(float), stream);
    hipMemsetAsync(out, 0, (size_t)n_nodes * NHID * sizeof(float), stream);
    spmm64_atomic<<<(n_edges * 16 + 255) / 256, 256, 0, stream>>>(row, col, vals, H, fAH, n_edges);
    gemm_tiled_relu<64, false><<<gemm_grid, 256, 0, stream>>>(fAH, W1, b1, fH1, n_nodes);
    spmm128_atomic<<<(n_edges * 32 + 255) / 256, 256, 0, stream>>>(row, col, vals, fH1, out, n_edges);
    gemm_tiled_relu<128, false><<<gemm_grid, 256, 0, stream>>>(out, W2, b2, out, n_nodes);
  }
}

// Round 8
// 310.269 us; speedup vs baseline: 14.6570x; 1.2913x over previous
//
#include <hip/hip_runtime.h>

// GCN: H2 = relu(A @ relu(A@H @ W1 + b1) @ W2 + b2)
// A: COO (row,col,vals), E=1.6M, N=100k, feats 64 -> 128 -> 128.
// R8: GEMMs moved to MFMA bf16 (LDS-free, B-frags preloaded in VGPRs from a
// pre-swizzled W buffer). SpMMs emit bf16 feature rows directly.

#define NFEAT 64
#define NHID 128
#define BSHIFT 9              // 512 rows per bucket
#define BROWS (1 << BSHIFT)
#define NB_MAX 256            // supports n_nodes <= 131072 (17-bit col pack)

typedef __attribute__((ext_vector_type(8))) short bf16x8;
typedef __attribute__((ext_vector_type(4))) float f32x4;

// ---------------- bf16 helpers ----------------
__device__ __forceinline__ unsigned short f2bf(float x) {
  unsigned u = __float_as_uint(x);
  unsigned r = (u + 0x7FFFu + ((u >> 16) & 1u)) >> 16;  // RNE
  return (unsigned short)r;
}
__device__ __forceinline__ float bf_lo(unsigned w) {
  return __uint_as_float(w << 16);
}
__device__ __forceinline__ float bf_hi(unsigned w) {
  return __uint_as_float(w & 0xFFFF0000u);
}
__device__ __forceinline__ unsigned pack2(float a, float b) {
  return (unsigned)f2bf(a) | ((unsigned)f2bf(b) << 16);
}

// f32 -> bf16 pack, 4 elems/thread.
__global__ __launch_bounds__(256) void tobf16_kernel(
    const float* __restrict__ src, unsigned short* __restrict__ dst, int n4) {
  for (int i = blockIdx.x * 256 + threadIdx.x; i < n4; i += gridDim.x * 256) {
    float4 a = ((const float4*)src)[i];
    ((uint2*)dst)[i] = make_uint2(pack2(a.x, a.y), pack2(a.z, a.w));
  }
}

// W[K x 128] f32 -> b-frag-swizzled bf16: Wsw[((kt*128 + n)*32 + q*8 + j)]
// = W[kt*32 + q*8 + j][n].  Lane (m,quad) then loads 16B contiguous.
__global__ __launch_bounds__(256) void wswizzle_kernel(
    const float* __restrict__ W, unsigned short* __restrict__ Wsw, int total) {
  for (int idx = blockIdx.x * 256 + threadIdx.x; idx < total; idx += gridDim.x * 256) {
    int j = idx & 7, q = (idx >> 3) & 3, nn = (idx >> 5) & 127, kt = idx >> 12;
    int k = kt * 32 + q * 8 + j;
    Wsw[idx] = f2bf(W[(size_t)k * 128 + nn]);
  }
}

// ---------------- bucket histogram (LDS-aggregated) ----------------
__global__ __launch_bounds__(256) void bhist_kernel(
    const int* __restrict__ row, int* __restrict__ bcnt, int n_edges, int nb) {
  __shared__ int h[NB_MAX];
  for (int i = threadIdx.x; i < NB_MAX; i += 256) h[i] = 0;
  __syncthreads();
  for (int e = blockIdx.x * 256 + threadIdx.x; e < n_edges; e += gridDim.x * 256)
    atomicAdd(&h[row[e] >> BSHIFT], 1);
  __syncthreads();
  for (int i = threadIdx.x; i < nb; i += 256)
    if (h[i]) atomicAdd(&bcnt[i], h[i]);
}

// ---------------- bucket scan -> bbase[nb+1], cur[nb], row_ptr[n] -----------
__global__ __launch_bounds__(NB_MAX) void bscan_kernel(
    const int* __restrict__ bcnt, int* __restrict__ bbase, int* __restrict__ cur,
    int* __restrict__ row_ptr, int nb, int n) {
  __shared__ int sm[NB_MAX];
  int t = threadIdx.x;
  int v = (t < nb) ? bcnt[t] : 0;
  sm[t] = v;
  __syncthreads();
  for (int off = 1; off < NB_MAX; off <<= 1) {
    int u = (t >= off) ? sm[t - off] : 0;
    __syncthreads();
    sm[t] += u;
    __syncthreads();
  }
  if (t < nb) {
    bbase[t] = sm[t] - v;
    cur[t] = sm[t] - v;
  }
  if (t == nb - 1) {
    bbase[nb] = sm[t];
    row_ptr[n] = sm[t];
  }
}

// ---------------- pass A: multi-split partition into buckets ----------------
__global__ __launch_bounds__(256) void partition_kernel(
    const int* __restrict__ row, const int* __restrict__ col,
    const float* __restrict__ vals, int* __restrict__ cur,
    int2* __restrict__ bedge, int n_edges) {
  __shared__ int h[NB_MAX], base[NB_MAX], rk[NB_MAX];
  for (int i = threadIdx.x; i < NB_MAX; i += 256) {
    h[i] = 0;
    rk[i] = 0;
  }
  __syncthreads();
  const int start = blockIdx.x * 256 + threadIdx.x;
  const int step = gridDim.x * 256;
  for (int e = start; e < n_edges; e += step)
    atomicAdd(&h[row[e] >> BSHIFT], 1);
  __syncthreads();
  for (int i = threadIdx.x; i < NB_MAX; i += 256)
    base[i] = h[i] ? atomicAdd(&cur[i], h[i]) : 0;
  __syncthreads();
  for (int e = start; e < n_edges; e += step) {
    int r = row[e];
    int b = r >> BSHIFT;
    int rl = r & (BROWS - 1);
    int p = base[b] + atomicAdd(&rk[b], 1);
    bedge[p] = make_int2((rl << 17) | col[e], __float_as_int(vals[e]));
  }
}

// ---------------- pass B: per-bucket exact CSR ----------------
__global__ __launch_bounds__(512) void bucket_csr_kernel(
    const int* __restrict__ bbase, const int2* __restrict__ bedge,
    int* __restrict__ row_ptr, int2* __restrict__ sedge, int n) {
  __shared__ int cnt[BROWS];
  __shared__ int sm[BROWS];
  const int b = blockIdx.x;
  const int t = threadIdx.x;
  const int beg = bbase[b], end = bbase[b + 1];
  cnt[t] = 0;
  __syncthreads();
  for (int j = beg + t; j < end; j += 512)
    atomicAdd(&cnt[((unsigned)bedge[j].x) >> 17], 1);
  __syncthreads();
  int v = cnt[t];
  sm[t] = v;
  __syncthreads();
  for (int off = 1; off < BROWS; off <<= 1) {
    int u = (t >= off) ? sm[t - off] : 0;
    __syncthreads();
    sm[t] += u;
    __syncthreads();
  }
  {
    int incl = sm[t];
    __syncthreads();
    sm[t] = incl - v;  // exclusive local base
  }
  int r = (b << BSHIFT) + t;
  if (r < n) row_ptr[r] = beg + sm[t];
  cnt[t] = 0;
  __syncthreads();
  for (int j = beg + t; j < end; j += 512) {
    int2 ev = bedge[j];
    int rl = ((unsigned)ev.x) >> 17;
    int rank = atomicAdd(&cnt[rl], 1);
    sedge[beg + sm[rl] + rank] = make_int2(ev.x & 0x1FFFF, ev.y);
  }
}

// ---------------- CSR gather SpMM, bf16 in / bf16 out ----------------
// 64 feats bf16 = 128 B/row: 8 lanes per row, one uint4 (8 bf16) per lane.
__global__ __launch_bounds__(256) void spmm64_csr_bf(
    const int* __restrict__ row_ptr, const int2* __restrict__ sedge,
    const unsigned short* __restrict__ Hbf, unsigned short* __restrict__ outbf,
    int n) {
  int tid = blockIdx.x * 256 + threadIdx.x;
  int r = tid >> 3;
  int f = tid & 7;
  if (r >= n) return;
  const uint4* Hq = (const uint4*)Hbf;  // 8 uint4 per 64-feat row
  int beg = row_ptr[r], end = row_ptr[r + 1];
  float acc[8] = {0.f, 0.f, 0.f, 0.f, 0.f, 0.f, 0.f, 0.f};
#pragma unroll 2
  for (int j = beg; j < end; ++j) {
    int2 ev = sedge[j];
    float v = __int_as_float(ev.y);
    uint4 q = Hq[(size_t)ev.x * 8 + f];
    acc[0] = fmaf(v, bf_lo(q.x), acc[0]);
    acc[1] = fmaf(v, bf_hi(q.x), acc[1]);
    acc[2] = fmaf(v, bf_lo(q.y), acc[2]);
    acc[3] = fmaf(v, bf_hi(q.y), acc[3]);
    acc[4] = fmaf(v, bf_lo(q.z), acc[4]);
    acc[5] = fmaf(v, bf_hi(q.z), acc[5]);
    acc[6] = fmaf(v, bf_lo(q.w), acc[6]);
    acc[7] = fmaf(v, bf_hi(q.w), acc[7]);
  }
  ((uint4*)outbf)[(size_t)r * 8 + f] =
      make_uint4(pack2(acc[0], acc[1]), pack2(acc[2], acc[3]),
                 pack2(acc[4], acc[5]), pack2(acc[6], acc[7]));
}

// 128 feats bf16 = 256 B/row: 16 lanes per row.
__global__ __launch_bounds__(256) void spmm128_csr_bf(
    const int* __restrict__ row_ptr, const int2* __restrict__ sedge,
    const unsigned short* __restrict__ Hbf, unsigned short* __restrict__ outbf,
    int n) {
  int tid = blockIdx.x * 256 + threadIdx.x;
  int r = tid >> 4;
  int f = tid & 15;
  if (r >= n) return;
  const uint4* Hq = (const uint4*)Hbf;  // 16 uint4 per 128-feat row
  int beg = row_ptr[r], end = row_ptr[r + 1];
  float acc[8] = {0.f, 0.f, 0.f, 0.f, 0.f, 0.f, 0.f, 0.f};
#pragma unroll 2
  for (int j = beg; j < end; ++j) {
    int2 ev = sedge[j];
    float v = __int_as_float(ev.y);
    uint4 q = Hq[(size_t)ev.x * 16 + f];
    acc[0] = fmaf(v, bf_lo(q.x), acc[0]);
    acc[1] = fmaf(v, bf_hi(q.x), acc[1]);
    acc[2] = fmaf(v, bf_lo(q.y), acc[2]);
    acc[3] = fmaf(v, bf_hi(q.y), acc[3]);
    acc[4] = fmaf(v, bf_lo(q.z), acc[4]);
    acc[5] = fmaf(v, bf_hi(q.z), acc[5]);
    acc[6] = fmaf(v, bf_lo(q.w), acc[6]);
    acc[7] = fmaf(v, bf_hi(q.w), acc[7]);
  }
  ((uint4*)outbf)[(size_t)r * 16 + f] =
      make_uint4(pack2(acc[0], acc[1]), pack2(acc[2], acc[3]),
                 pack2(acc[4], acc[5]), pack2(acc[6], acc[7]));
}

// ---------------- MFMA bf16 GEMM + bias + relu (LDS-free) ----------------
// C[n x 128] = relu(Abf[n x K] @ W + b). One wave = 16 rows x 128 cols.
// B-frags preloaded into VGPRs from Wsw (b-frag-order swizzled, coalesced).
// Layouts (m89/m91-verified): A-frag A[m=lane&15][k=quad*8+j];
// B-frag B[k=quad*8+j][n=lane&15]; D reg i -> row=quad*4+i, col=lane&15.
template <int K, bool BF16OUT>
__global__ __launch_bounds__(256) void gemm_mfma_relu(
    const unsigned short* __restrict__ Abf,
    const unsigned short* __restrict__ Wsw,
    const float* __restrict__ b, void* __restrict__ out_v, int n) {
  constexpr int KT = K / 32;
  const int lane = threadIdx.x & 63;
  const int wave = threadIdx.x >> 6;
  const int m = lane & 15;
  const int quad = lane >> 4;
  const int r0 = blockIdx.x * 64 + wave * 16;

  // Preload all B fragments (KT x 8 col-tiles).
  bf16x8 bfr[KT][8];
#pragma unroll
  for (int kt = 0; kt < KT; ++kt)
#pragma unroll
    for (int c = 0; c < 8; ++c)
      bfr[kt][c] = *(const bf16x8*)(Wsw + ((size_t)(kt * 128 + c * 16 + m)) * 32 + quad * 8);

  f32x4 acc[8];
#pragma unroll
  for (int c = 0; c < 8; ++c) acc[c] = (f32x4){0.f, 0.f, 0.f, 0.f};

  int row = r0 + m;
  if (row >= n) row = n - 1;  // clamped garbage only affects guarded rows
  const uint4* Arow = (const uint4*)(Abf + (size_t)row * K);
#pragma unroll
  for (int kt = 0; kt < KT; ++kt) {
    bf16x8 a = *(const bf16x8*)&Arow[kt * 4 + quad];
#pragma unroll
    for (int c = 0; c < 8; ++c)
      acc[c] = __builtin_amdgcn_mfma_f32_16x16x32_bf16(a, bfr[kt][c], acc[c], 0, 0, 0);
  }

#pragma unroll
  for (int c = 0; c < 8; ++c) {
    float bias = b[c * 16 + m];
#pragma unroll
    for (int i = 0; i < 4; ++i) {
      int rr = r0 + quad * 4 + i;
      if (rr >= n) continue;
      float v = fmaxf(acc[c][i] + bias, 0.f);
      if (BF16OUT)
        ((unsigned short*)out_v)[(size_t)rr * 128 + c * 16 + m] = f2bf(v);
      else
        ((float*)out_v)[(size_t)rr * 128 + c * 16 + m] = v;
    }
  }
}

// ---------------- fallback path (f32 atomics + f32 VALU GEMM) ----------------
__global__ __launch_bounds__(256) void spmm64_atomic(
    const int* __restrict__ row, const int* __restrict__ col,
    const float* __restrict__ vals, const float* __restrict__ Hin,
    float* __restrict__ out, int n_edges) {
  int tid = blockIdx.x * 256 + threadIdx.x;
  int e = tid >> 4, f = tid & 15;
  if (e >= n_edges) return;
  int c = col[e], r = row[e];
  float v = vals[e];
  float4 h = ((const float4*)Hin)[(size_t)c * 16 + f];
  float* o = out + (size_t)r * 64 + f * 4;
  atomicAdd(o + 0, v * h.x);
  atomicAdd(o + 1, v * h.y);
  atomicAdd(o + 2, v * h.z);
  atomicAdd(o + 3, v * h.w);
}

__global__ __launch_bounds__(256) void spmm128_atomic(
    const int* __restrict__ row, const int* __restrict__ col,
    const float* __restrict__ vals, const float* __restrict__ Hin,
    float* __restrict__ out, int n_edges) {
  int tid = blockIdx.x * 256 + threadIdx.x;
  int e = tid >> 5, f = tid & 31;
  if (e >= n_edges) return;
  int c = col[e], r = row[e];
  float v = vals[e];
  float4 h = ((const float4*)Hin)[(size_t)c * 32 + f];
  float* o = out + (size_t)r * 128 + f * 4;
  atomicAdd(o + 0, v * h.x);
  atomicAdd(o + 1, v * h.y);
  atomicAdd(o + 2, v * h.z);
  atomicAdd(o + 3, v * h.w);
}

template <int K>
__global__ __launch_bounds__(256) void gemm_tiled_relu(
    const float* __restrict__ A, const float* __restrict__ W,
    const float* __restrict__ b, float* __restrict__ out, int n) {
  constexpr int KB = 32;
  constexpr int RP = 132;
  __shared__ float As[KB][RP];
  __shared__ float Ws[KB][128];
  const int t = threadIdx.x;
  const int tx = t & 15, ty = t >> 4;
  const int r0 = blockIdx.x * 128;
  float4 acc0[8], acc1[8];
#pragma unroll
  for (int i = 0; i < 8; ++i) {
    acc0[i] = make_float4(0.f, 0.f, 0.f, 0.f);
    acc1[i] = make_float4(0.f, 0.f, 0.f, 0.f);
  }
  for (int k0 = 0; k0 < K; k0 += KB) {
#pragma unroll
    for (int q = 0; q < 4; ++q) {
      int f = q * 256 + t;
      int kk = f >> 5, cv = f & 31;
      ((float4*)&Ws[kk][0])[cv] = ((const float4*)(W + (size_t)(k0 + kk) * 128))[cv];
    }
#pragma unroll
    for (int q = 0; q < 4; ++q) {
      int f = q * 256 + t;
      int r = f >> 3, kv = f & 7;
      float4 av = make_float4(0.f, 0.f, 0.f, 0.f);
      if (r0 + r < n) av = ((const float4*)(A + (size_t)(r0 + r) * K + k0))[kv];
      As[4 * kv + 0][r] = av.x;
      As[4 * kv + 1][r] = av.y;
      As[4 * kv + 2][r] = av.z;
      As[4 * kv + 3][r] = av.w;
    }
    __syncthreads();
#pragma unroll
    for (int k = 0; k < KB; ++k) {
      float4 w0 = *((const float4*)&Ws[k][4 * tx]);
      float4 w1 = *((const float4*)&Ws[k][64 + 4 * tx]);
#pragma unroll
      for (int i = 0; i < 8; ++i) {
        float a = As[k][ty + 16 * i];
        acc0[i].x = fmaf(a, w0.x, acc0[i].x);
        acc0[i].y = fmaf(a, w0.y, acc0[i].y);
        acc0[i].z = fmaf(a, w0.z, acc0[i].z);
        acc0[i].w = fmaf(a, w0.w, acc0[i].w);
        acc1[i].x = fmaf(a, w1.x, acc1[i].x);
        acc1[i].y = fmaf(a, w1.y, acc1[i].y);
        acc1[i].z = fmaf(a, w1.z, acc1[i].z);
        acc1[i].w = fmaf(a, w1.w, acc1[i].w);
      }
    }
    __syncthreads();
  }
  float4 bb0 = ((const float4*)b)[tx];
  float4 bb1 = ((const float4*)(b + 64))[tx];
#pragma unroll
  for (int i = 0; i < 8; ++i) {
    int r = r0 + ty + 16 * i;
    if (r >= n) continue;
    float4 o0, o1;
    o0.x = fmaxf(acc0[i].x + bb0.x, 0.f);
    o0.y = fmaxf(acc0[i].y + bb0.y, 0.f);
    o0.z = fmaxf(acc0[i].z + bb0.z, 0.f);
    o0.w = fmaxf(acc0[i].w + bb0.w, 0.f);
    o1.x = fmaxf(acc1[i].x + bb1.x, 0.f);
    o1.y = fmaxf(acc1[i].y + bb1.y, 0.f);
    o1.z = fmaxf(acc1[i].z + bb1.z, 0.f);
    o1.w = fmaxf(acc1[i].w + bb1.w, 0.f);
    ((float4*)(out + (size_t)r * 128))[tx] = o0;
    ((float4*)(out + (size_t)r * 128 + 64))[tx] = o1;
  }
}

extern "C" void kernel_launch(void* const* d_in, const int* in_sizes, int n_in,
                              void* d_out, int out_size, void* d_ws, size_t ws_size,
                              hipStream_t stream) {
  const int* row = (const int*)d_in[0];
  const int* col = (const int*)d_in[1];
  const float* vals = (const float*)d_in[2];
  const float* H = (const float*)d_in[3];
  const float* W1 = (const float*)d_in[4];
  const float* b1 = (const float*)d_in[5];
  const float* W2 = (const float*)d_in[6];
  const float* b2 = (const float*)d_in[7];
  float* out = (float*)d_out;

  const int n_edges = in_sizes[0];
  const int n_nodes = in_sizes[3] / NFEAT;
  const int nb = (n_nodes + BROWS - 1) / BROWS;
  const int mfma_grid = (n_nodes + 63) / 64;

  // Workspace layout (CSR path):
  // slab0: max(bedge E*8, AH1bf N*128*2)  -- bedge dead before AH1bf written
  // | Hbf N*64*2 | AHbf N*64*2 | H1bf N*128*2 | sedge E*8
  // | Wsw1 64*128*2 | Wsw2 128*128*2 | bcnt | bbase | cur | row_ptr
  size_t off = 0;
  char* base = (char*)d_ws;
  char* slab0 = base;
  size_t slab0_sz = (size_t)n_edges * 8;
  size_t ah1_sz = (size_t)n_nodes * NHID * 2;
  if (ah1_sz > slab0_sz) slab0_sz = ah1_sz;
  off += slab0_sz;
  unsigned short* Hbf = (unsigned short*)(base + off);  off += (size_t)n_nodes * NFEAT * 2;
  unsigned short* AHbf = (unsigned short*)(base + off); off += (size_t)n_nodes * NFEAT * 2;
  unsigned short* H1bf = (unsigned short*)(base + off); off += (size_t)n_nodes * NHID * 2;
  int2* sedge = (int2*)(base + off);  off += (size_t)n_edges * 8;
  unsigned short* Wsw1 = (unsigned short*)(base + off); off += 64 * 128 * 2;
  unsigned short* Wsw2 = (unsigned short*)(base + off); off += 128 * 128 * 2;
  int* bcnt = (int*)(base + off);     off += NB_MAX * 4;
  int* bbase = (int*)(base + off);    off += (NB_MAX + 1) * 4;
  int* cur = (int*)(base + off);      off += NB_MAX * 4;
  int* row_ptr = (int*)(base + off);  off += ((size_t)n_nodes + 1) * 4;
  const size_t needed = off;
  int2* bedge = (int2*)slab0;
  unsigned short* AH1bf = (unsigned short*)slab0;

  if (ws_size >= needed && nb <= NB_MAX && n_nodes <= (1 << 17)) {
    // ---- bucket-sort CSR build ----
    hipMemsetAsync(bcnt, 0, NB_MAX * sizeof(int), stream);
    bhist_kernel<<<256, 256, 0, stream>>>(row, bcnt, n_edges, nb);
    bscan_kernel<<<1, NB_MAX, 0, stream>>>(bcnt, bbase, cur, row_ptr, nb, n_nodes);
    partition_kernel<<<256, 256, 0, stream>>>(row, col, vals, cur, bedge, n_edges);
    bucket_csr_kernel<<<nb, 512, 0, stream>>>(bbase, bedge, row_ptr, sedge, n_nodes);

    // Precision prep: H -> bf16, W1/W2 -> swizzled bf16.
    tobf16_kernel<<<1024, 256, 0, stream>>>(H, Hbf, n_nodes * NFEAT / 4);
    wswizzle_kernel<<<32, 256, 0, stream>>>(W1, Wsw1, 64 * 128);
    wswizzle_kernel<<<64, 256, 0, stream>>>(W2, Wsw2, 128 * 128);

    // Layer 1: AHbf = bf16(A @ Hbf) ; H1bf = bf16(relu(AHbf @ W1 + b1))
    spmm64_csr_bf<<<(n_nodes * 8 + 255) / 256, 256, 0, stream>>>(
        row_ptr, sedge, Hbf, AHbf, n_nodes);
    gemm_mfma_relu<64, true><<<mfma_grid, 256, 0, stream>>>(
        AHbf, Wsw1, b1, H1bf, n_nodes);
    // Layer 2: AH1bf = bf16(A @ H1bf) ; H2 = relu(AH1bf @ W2 + b2) -> d_out
    spmm128_csr_bf<<<(n_nodes * 16 + 255) / 256, 256, 0, stream>>>(
        row_ptr, sedge, H1bf, AH1bf, n_nodes);
    gemm_mfma_relu<128, false><<<mfma_grid, 256, 0, stream>>>(
        AH1bf, Wsw2, b2, out, n_nodes);
  } else {
    // ---- fallback: atomic scatter path (all f32) ----
    float* fAH = (float*)d_ws;
    float* fH1 = fAH + (size_t)n_nodes * NFEAT;
    hipMemsetAsync(fAH, 0, (size_t)n_nodes * NFEAT * sizeof(float), stream);
    hipMemsetAsync(out, 0, (size_t)n_nodes * NHID * sizeof(float), stream);
    spmm64_atomic<<<(n_edges * 16 + 255) / 256, 256, 0, stream>>>(row, col, vals, H, fAH, n_edges);
    gemm_tiled_relu<64><<<(n_nodes + 127) / 128, 256, 0, stream>>>(fAH, W1, b1, fH1, n_nodes);
    spmm128_atomic<<<(n_edges * 32 + 255) / 256, 256, 0, stream>>>(row, col, vals, fH1, out, n_edges);
    gemm_tiled_relu<128><<<(n_nodes + 127) / 128, 256, 0, stream>>>(out, W2, b2, out, n_nodes);
  }
}

// Round 9
// 290.790 us; speedup vs baseline: 15.6388x; 1.0670x over previous
//
#include <hip/hip_runtime.h>

// GCN: H2 = relu(A @ relu(A@H @ W1 + b1) @ W2 + b2)
// A: COO (row,col,vals), E=1.6M, N=100k, feats 64 -> 128 -> 128.
// R9: gathered operands (H, H1) stored as OCP fp8 e4m3 via HW converters ->
// halves SpMM gather bytes again (compulsory per-XCD FETCH was the limit).
// f32 accumulate; GEMM operands stay bf16; edge vals stay f32.

#define NFEAT 64
#define NHID 128
#define BSHIFT 9              // 512 rows per bucket
#define BROWS (1 << BSHIFT)
#define NB_MAX 256            // supports n_nodes <= 131072 (17-bit col pack)

typedef __attribute__((ext_vector_type(8))) short bf16x8;
typedef __attribute__((ext_vector_type(4))) float f32x4;
typedef __attribute__((ext_vector_type(2))) float f32x2;

// ---------------- bf16 helpers ----------------
__device__ __forceinline__ unsigned short f2bf(float x) {
  unsigned u = __float_as_uint(x);
  unsigned r = (u + 0x7FFFu + ((u >> 16) & 1u)) >> 16;  // RNE
  return (unsigned short)r;
}
__device__ __forceinline__ unsigned pack2(float a, float b) {
  return (unsigned)f2bf(a) | ((unsigned)f2bf(b) << 16);
}

// ---------------- fp8 e4m3 helpers (HW cvt) ----------------
__device__ __forceinline__ unsigned pk_fp8x4(float a, float b, float c, float d) {
  int w = __builtin_amdgcn_cvt_pk_fp8_f32(a, b, 0, false);   // bytes 0,1
  w = __builtin_amdgcn_cvt_pk_fp8_f32(c, d, w, true);        // bytes 2,3
  return (unsigned)w;
}
__device__ __forceinline__ unsigned char f2fp8(float x) {
  return (unsigned char)(__builtin_amdgcn_cvt_pk_fp8_f32(x, 0.f, 0, false) & 0xFF);
}

// f32 -> fp8 pack, 8 elems/thread.
__global__ __launch_bounds__(256) void tofp8_kernel(
    const float* __restrict__ src, unsigned char* __restrict__ dst, int n8) {
  for (int i = blockIdx.x * 256 + threadIdx.x; i < n8; i += gridDim.x * 256) {
    float4 a = ((const float4*)src)[2 * i];
    float4 b = ((const float4*)src)[2 * i + 1];
    ((uint2*)dst)[i] = make_uint2(pk_fp8x4(a.x, a.y, a.z, a.w),
                                  pk_fp8x4(b.x, b.y, b.z, b.w));
  }
}

// W[K x 128] f32 -> b-frag-swizzled bf16: Wsw[((kt*128 + n)*32 + q*8 + j)]
// = W[kt*32 + q*8 + j][n].  Lane (m,quad) then loads 16B contiguous.
__global__ __launch_bounds__(256) void wswizzle_kernel(
    const float* __restrict__ W, unsigned short* __restrict__ Wsw, int total) {
  for (int idx = blockIdx.x * 256 + threadIdx.x; idx < total; idx += gridDim.x * 256) {
    int j = idx & 7, q = (idx >> 3) & 3, nn = (idx >> 5) & 127, kt = idx >> 12;
    int k = kt * 32 + q * 8 + j;
    Wsw[idx] = f2bf(W[(size_t)k * 128 + nn]);
  }
}

// ---------------- bucket histogram (LDS-aggregated) ----------------
__global__ __launch_bounds__(256) void bhist_kernel(
    const int* __restrict__ row, int* __restrict__ bcnt, int n_edges, int nb) {
  __shared__ int h[NB_MAX];
  for (int i = threadIdx.x; i < NB_MAX; i += 256) h[i] = 0;
  __syncthreads();
  for (int e = blockIdx.x * 256 + threadIdx.x; e < n_edges; e += gridDim.x * 256)
    atomicAdd(&h[row[e] >> BSHIFT], 1);
  __syncthreads();
  for (int i = threadIdx.x; i < nb; i += 256)
    if (h[i]) atomicAdd(&bcnt[i], h[i]);
}

// ---------------- bucket scan -> bbase[nb+1], cur[nb], row_ptr[n] -----------
__global__ __launch_bounds__(NB_MAX) void bscan_kernel(
    const int* __restrict__ bcnt, int* __restrict__ bbase, int* __restrict__ cur,
    int* __restrict__ row_ptr, int nb, int n) {
  __shared__ int sm[NB_MAX];
  int t = threadIdx.x;
  int v = (t < nb) ? bcnt[t] : 0;
  sm[t] = v;
  __syncthreads();
  for (int off = 1; off < NB_MAX; off <<= 1) {
    int u = (t >= off) ? sm[t - off] : 0;
    __syncthreads();
    sm[t] += u;
    __syncthreads();
  }
  if (t < nb) {
    bbase[t] = sm[t] - v;
    cur[t] = sm[t] - v;
  }
  if (t == nb - 1) {
    bbase[nb] = sm[t];
    row_ptr[n] = sm[t];
  }
}

// ---------------- pass A: multi-split partition into buckets ----------------
__global__ __launch_bounds__(256) void partition_kernel(
    const int* __restrict__ row, const int* __restrict__ col,
    const float* __restrict__ vals, int* __restrict__ cur,
    int2* __restrict__ bedge, int n_edges) {
  __shared__ int h[NB_MAX], base[NB_MAX], rk[NB_MAX];
  for (int i = threadIdx.x; i < NB_MAX; i += 256) {
    h[i] = 0;
    rk[i] = 0;
  }
  __syncthreads();
  const int start = blockIdx.x * 256 + threadIdx.x;
  const int step = gridDim.x * 256;
  for (int e = start; e < n_edges; e += step)
    atomicAdd(&h[row[e] >> BSHIFT], 1);
  __syncthreads();
  for (int i = threadIdx.x; i < NB_MAX; i += 256)
    base[i] = h[i] ? atomicAdd(&cur[i], h[i]) : 0;
  __syncthreads();
  for (int e = start; e < n_edges; e += step) {
    int r = row[e];
    int b = r >> BSHIFT;
    int rl = r & (BROWS - 1);
    int p = base[b] + atomicAdd(&rk[b], 1);
    bedge[p] = make_int2((rl << 17) | col[e], __float_as_int(vals[e]));
  }
}

// ---------------- pass B: per-bucket exact CSR ----------------
__global__ __launch_bounds__(512) void bucket_csr_kernel(
    const int* __restrict__ bbase, const int2* __restrict__ bedge,
    int* __restrict__ row_ptr, int2* __restrict__ sedge, int n) {
  __shared__ int cnt[BROWS];
  __shared__ int sm[BROWS];
  const int b = blockIdx.x;
  const int t = threadIdx.x;
  const int beg = bbase[b], end = bbase[b + 1];
  cnt[t] = 0;
  __syncthreads();
  for (int j = beg + t; j < end; j += 512)
    atomicAdd(&cnt[((unsigned)bedge[j].x) >> 17], 1);
  __syncthreads();
  int v = cnt[t];
  sm[t] = v;
  __syncthreads();
  for (int off = 1; off < BROWS; off <<= 1) {
    int u = (t >= off) ? sm[t - off] : 0;
    __syncthreads();
    sm[t] += u;
    __syncthreads();
  }
  {
    int incl = sm[t];
    __syncthreads();
    sm[t] = incl - v;  // exclusive local base
  }
  int r = (b << BSHIFT) + t;
  if (r < n) row_ptr[r] = beg + sm[t];
  cnt[t] = 0;
  __syncthreads();
  for (int j = beg + t; j < end; j += 512) {
    int2 ev = bedge[j];
    int rl = ((unsigned)ev.x) >> 17;
    int rank = atomicAdd(&cnt[rl], 1);
    sedge[beg + sm[rl] + rank] = make_int2(ev.x & 0x1FFFF, ev.y);
  }
}

// ---------------- CSR gather SpMM, fp8 in / bf16 out ----------------
// 64 feats fp8 = 64 B/row: 8 lanes per row, one uint2 (8 fp8) per lane.
__global__ __launch_bounds__(256) void spmm64_csr_f8(
    const int* __restrict__ row_ptr, const int2* __restrict__ sedge,
    const unsigned char* __restrict__ Hf8, unsigned short* __restrict__ outbf,
    int n) {
  int tid = blockIdx.x * 256 + threadIdx.x;
  int r = tid >> 3;
  int f = tid & 7;
  if (r >= n) return;
  const uint2* Hq = (const uint2*)Hf8;  // 8 uint2 per 64-feat row
  int beg = row_ptr[r], end = row_ptr[r + 1];
  float acc[8] = {0.f, 0.f, 0.f, 0.f, 0.f, 0.f, 0.f, 0.f};
#pragma unroll 2
  for (int j = beg; j < end; ++j) {
    int2 ev = sedge[j];
    float v = __int_as_float(ev.y);
    uint2 q = Hq[(size_t)ev.x * 8 + f];
    f32x2 p0 = __builtin_amdgcn_cvt_pk_f32_fp8(q.x, false);
    f32x2 p1 = __builtin_amdgcn_cvt_pk_f32_fp8(q.x, true);
    f32x2 p2 = __builtin_amdgcn_cvt_pk_f32_fp8(q.y, false);
    f32x2 p3 = __builtin_amdgcn_cvt_pk_f32_fp8(q.y, true);
    acc[0] = fmaf(v, p0.x, acc[0]);
    acc[1] = fmaf(v, p0.y, acc[1]);
    acc[2] = fmaf(v, p1.x, acc[2]);
    acc[3] = fmaf(v, p1.y, acc[3]);
    acc[4] = fmaf(v, p2.x, acc[4]);
    acc[5] = fmaf(v, p2.y, acc[5]);
    acc[6] = fmaf(v, p3.x, acc[6]);
    acc[7] = fmaf(v, p3.y, acc[7]);
  }
  ((uint4*)outbf)[(size_t)r * 8 + f] =
      make_uint4(pack2(acc[0], acc[1]), pack2(acc[2], acc[3]),
                 pack2(acc[4], acc[5]), pack2(acc[6], acc[7]));
}

// 128 feats fp8 = 128 B/row: 16 lanes per row.
__global__ __launch_bounds__(256) void spmm128_csr_f8(
    const int* __restrict__ row_ptr, const int2* __restrict__ sedge,
    const unsigned char* __restrict__ Hf8, unsigned short* __restrict__ outbf,
    int n) {
  int tid = blockIdx.x * 256 + threadIdx.x;
  int r = tid >> 4;
  int f = tid & 15;
  if (r >= n) return;
  const uint2* Hq = (const uint2*)Hf8;  // 16 uint2 per 128-feat row
  int beg = row_ptr[r], end = row_ptr[r + 1];
  float acc[8] = {0.f, 0.f, 0.f, 0.f, 0.f, 0.f, 0.f, 0.f};
#pragma unroll 2
  for (int j = beg; j < end; ++j) {
    int2 ev = sedge[j];
    float v = __int_as_float(ev.y);
    uint2 q = Hq[(size_t)ev.x * 16 + f];
    f32x2 p0 = __builtin_amdgcn_cvt_pk_f32_fp8(q.x, false);
    f32x2 p1 = __builtin_amdgcn_cvt_pk_f32_fp8(q.x, true);
    f32x2 p2 = __builtin_amdgcn_cvt_pk_f32_fp8(q.y, false);
    f32x2 p3 = __builtin_amdgcn_cvt_pk_f32_fp8(q.y, true);
    acc[0] = fmaf(v, p0.x, acc[0]);
    acc[1] = fmaf(v, p0.y, acc[1]);
    acc[2] = fmaf(v, p1.x, acc[2]);
    acc[3] = fmaf(v, p1.y, acc[3]);
    acc[4] = fmaf(v, p2.x, acc[4]);
    acc[5] = fmaf(v, p2.y, acc[5]);
    acc[6] = fmaf(v, p3.x, acc[6]);
    acc[7] = fmaf(v, p3.y, acc[7]);
  }
  ((uint4*)outbf)[(size_t)r * 16 + f] =
      make_uint4(pack2(acc[0], acc[1]), pack2(acc[2], acc[3]),
                 pack2(acc[4], acc[5]), pack2(acc[6], acc[7]));
}

// ---------------- MFMA bf16 GEMM + bias + relu (LDS-free) ----------------
// OUT mode: 0 = f32, 2 = fp8 (for H1 consumed by spmm128_csr_f8).
// One wave = 16 rows x 128 cols; B-frags preloaded from swizzled Wsw.
template <int K, int OUTMODE>
__global__ __launch_bounds__(256) void gemm_mfma_relu(
    const unsigned short* __restrict__ Abf,
    const unsigned short* __restrict__ Wsw,
    const float* __restrict__ b, void* __restrict__ out_v, int n) {
  constexpr int KT = K / 32;
  const int lane = threadIdx.x & 63;
  const int wave = threadIdx.x >> 6;
  const int m = lane & 15;
  const int quad = lane >> 4;
  const int r0 = blockIdx.x * 64 + wave * 16;

  bf16x8 bfr[KT][8];
#pragma unroll
  for (int kt = 0; kt < KT; ++kt)
#pragma unroll
    for (int c = 0; c < 8; ++c)
      bfr[kt][c] = *(const bf16x8*)(Wsw + ((size_t)(kt * 128 + c * 16 + m)) * 32 + quad * 8);

  f32x4 acc[8];
#pragma unroll
  for (int c = 0; c < 8; ++c) acc[c] = (f32x4){0.f, 0.f, 0.f, 0.f};

  int row = r0 + m;
  if (row >= n) row = n - 1;
  const uint4* Arow = (const uint4*)(Abf + (size_t)row * K);
#pragma unroll
  for (int kt = 0; kt < KT; ++kt) {
    bf16x8 a = *(const bf16x8*)&Arow[kt * 4 + quad];
#pragma unroll
    for (int c = 0; c < 8; ++c)
      acc[c] = __builtin_amdgcn_mfma_f32_16x16x32_bf16(a, bfr[kt][c], acc[c], 0, 0, 0);
  }

#pragma unroll
  for (int c = 0; c < 8; ++c) {
    float bias = b[c * 16 + m];
#pragma unroll
    for (int i = 0; i < 4; ++i) {
      int rr = r0 + quad * 4 + i;
      if (rr >= n) continue;
      float v = fmaxf(acc[c][i] + bias, 0.f);
      if (OUTMODE == 2)
        ((unsigned char*)out_v)[(size_t)rr * 128 + c * 16 + m] = f2fp8(v);
      else
        ((float*)out_v)[(size_t)rr * 128 + c * 16 + m] = v;
    }
  }
}

// ---------------- fallback path (f32 atomics + f32 VALU GEMM) ----------------
__global__ __launch_bounds__(256) void spmm64_atomic(
    const int* __restrict__ row, const int* __restrict__ col,
    const float* __restrict__ vals, const float* __restrict__ Hin,
    float* __restrict__ out, int n_edges) {
  int tid = blockIdx.x * 256 + threadIdx.x;
  int e = tid >> 4, f = tid & 15;
  if (e >= n_edges) return;
  int c = col[e], r = row[e];
  float v = vals[e];
  float4 h = ((const float4*)Hin)[(size_t)c * 16 + f];
  float* o = out + (size_t)r * 64 + f * 4;
  atomicAdd(o + 0, v * h.x);
  atomicAdd(o + 1, v * h.y);
  atomicAdd(o + 2, v * h.z);
  atomicAdd(o + 3, v * h.w);
}

__global__ __launch_bounds__(256) void spmm128_atomic(
    const int* __restrict__ row, const int* __restrict__ col,
    const float* __restrict__ vals, const float* __restrict__ Hin,
    float* __restrict__ out, int n_edges) {
  int tid = blockIdx.x * 256 + threadIdx.x;
  int e = tid >> 5, f = tid & 31;
  if (e >= n_edges) return;
  int c = col[e], r = row[e];
  float v = vals[e];
  float4 h = ((const float4*)Hin)[(size_t)c * 32 + f];
  float* o = out + (size_t)r * 128 + f * 4;
  atomicAdd(o + 0, v * h.x);
  atomicAdd(o + 1, v * h.y);
  atomicAdd(o + 2, v * h.z);
  atomicAdd(o + 3, v * h.w);
}

template <int K>
__global__ __launch_bounds__(256) void gemm_tiled_relu(
    const float* __restrict__ A, const float* __restrict__ W,
    const float* __restrict__ b, float* __restrict__ out, int n) {
  constexpr int KB = 32;
  constexpr int RP = 132;
  __shared__ float As[KB][RP];
  __shared__ float Ws[KB][128];
  const int t = threadIdx.x;
  const int tx = t & 15, ty = t >> 4;
  const int r0 = blockIdx.x * 128;
  float4 acc0[8], acc1[8];
#pragma unroll
  for (int i = 0; i < 8; ++i) {
    acc0[i] = make_float4(0.f, 0.f, 0.f, 0.f);
    acc1[i] = make_float4(0.f, 0.f, 0.f, 0.f);
  }
  for (int k0 = 0; k0 < K; k0 += KB) {
#pragma unroll
    for (int q = 0; q < 4; ++q) {
      int f = q * 256 + t;
      int kk = f >> 5, cv = f & 31;
      ((float4*)&Ws[kk][0])[cv] = ((const float4*)(W + (size_t)(k0 + kk) * 128))[cv];
    }
#pragma unroll
    for (int q = 0; q < 4; ++q) {
      int f = q * 256 + t;
      int r = f >> 3, kv = f & 7;
      float4 av = make_float4(0.f, 0.f, 0.f, 0.f);
      if (r0 + r < n) av = ((const float4*)(A + (size_t)(r0 + r) * K + k0))[kv];
      As[4 * kv + 0][r] = av.x;
      As[4 * kv + 1][r] = av.y;
      As[4 * kv + 2][r] = av.z;
      As[4 * kv + 3][r] = av.w;
    }
    __syncthreads();
#pragma unroll
    for (int k = 0; k < KB; ++k) {
      float4 w0 = *((const float4*)&Ws[k][4 * tx]);
      float4 w1 = *((const float4*)&Ws[k][64 + 4 * tx]);
#pragma unroll
      for (int i = 0; i < 8; ++i) {
        float a = As[k][ty + 16 * i];
        acc0[i].x = fmaf(a, w0.x, acc0[i].x);
        acc0[i].y = fmaf(a, w0.y, acc0[i].y);
        acc0[i].z = fmaf(a, w0.z, acc0[i].z);
        acc0[i].w = fmaf(a, w0.w, acc0[i].w);
        acc1[i].x = fmaf(a, w1.x, acc1[i].x);
        acc1[i].y = fmaf(a, w1.y, acc1[i].y);
        acc1[i].z = fmaf(a, w1.z, acc1[i].z);
        acc1[i].w = fmaf(a, w1.w, acc1[i].w);
      }
    }
    __syncthreads();
  }
  float4 bb0 = ((const float4*)b)[tx];
  float4 bb1 = ((const float4*)(b + 64))[tx];
#pragma unroll
  for (int i = 0; i < 8; ++i) {
    int r = r0 + ty + 16 * i;
    if (r >= n) continue;
    float4 o0, o1;
    o0.x = fmaxf(acc0[i].x + bb0.x, 0.f);
    o0.y = fmaxf(acc0[i].y + bb0.y, 0.f);
    o0.z = fmaxf(acc0[i].z + bb0.z, 0.f);
    o0.w = fmaxf(acc0[i].w + bb0.w, 0.f);
    o1.x = fmaxf(acc1[i].x + bb1.x, 0.f);
    o1.y = fmaxf(acc1[i].y + bb1.y, 0.f);
    o1.z = fmaxf(acc1[i].z + bb1.z, 0.f);
    o1.w = fmaxf(acc1[i].w + bb1.w, 0.f);
    ((float4*)(out + (size_t)r * 128))[tx] = o0;
    ((float4*)(out + (size_t)r * 128 + 64))[tx] = o1;
  }
}

extern "C" void kernel_launch(void* const* d_in, const int* in_sizes, int n_in,
                              void* d_out, int out_size, void* d_ws, size_t ws_size,
                              hipStream_t stream) {
  const int* row = (const int*)d_in[0];
  const int* col = (const int*)d_in[1];
  const float* vals = (const float*)d_in[2];
  const float* H = (const float*)d_in[3];
  const float* W1 = (const float*)d_in[4];
  const float* b1 = (const float*)d_in[5];
  const float* W2 = (const float*)d_in[6];
  const float* b2 = (const float*)d_in[7];
  float* out = (float*)d_out;

  const int n_edges = in_sizes[0];
  const int n_nodes = in_sizes[3] / NFEAT;
  const int nb = (n_nodes + BROWS - 1) / BROWS;
  const int mfma_grid = (n_nodes + 63) / 64;

  // Workspace layout (CSR path):
  // slab0: max(bedge E*8, AH1bf N*128*2)  -- bedge dead before AH1bf written
  // | Hf8 N*64 | H1f8 N*128 | AHbf N*64*2 | sedge E*8
  // | Wsw1 | Wsw2 | bcnt | bbase | cur | row_ptr
  size_t off = 0;
  char* base = (char*)d_ws;
  char* slab0 = base;
  size_t slab0_sz = (size_t)n_edges * 8;
  size_t ah1_sz = (size_t)n_nodes * NHID * 2;
  if (ah1_sz > slab0_sz) slab0_sz = ah1_sz;
  off += slab0_sz;
  unsigned char* Hf8 = (unsigned char*)(base + off);   off += (size_t)n_nodes * NFEAT;
  unsigned char* H1f8 = (unsigned char*)(base + off);  off += (size_t)n_nodes * NHID;
  unsigned short* AHbf = (unsigned short*)(base + off); off += (size_t)n_nodes * NFEAT * 2;
  int2* sedge = (int2*)(base + off);  off += (size_t)n_edges * 8;
  unsigned short* Wsw1 = (unsigned short*)(base + off); off += 64 * 128 * 2;
  unsigned short* Wsw2 = (unsigned short*)(base + off); off += 128 * 128 * 2;
  int* bcnt = (int*)(base + off);     off += NB_MAX * 4;
  int* bbase = (int*)(base + off);    off += (NB_MAX + 1) * 4;
  int* cur = (int*)(base + off);      off += NB_MAX * 4;
  int* row_ptr = (int*)(base + off);  off += ((size_t)n_nodes + 1) * 4;
  const size_t needed = off;
  int2* bedge = (int2*)slab0;
  unsigned short* AH1bf = (unsigned short*)slab0;

  if (ws_size >= needed && nb <= NB_MAX && n_nodes <= (1 << 17)) {
    // ---- bucket-sort CSR build ----
    hipMemsetAsync(bcnt, 0, NB_MAX * sizeof(int), stream);
    bhist_kernel<<<256, 256, 0, stream>>>(row, bcnt, n_edges, nb);
    bscan_kernel<<<1, NB_MAX, 0, stream>>>(bcnt, bbase, cur, row_ptr, nb, n_nodes);
    partition_kernel<<<256, 256, 0, stream>>>(row, col, vals, cur, bedge, n_edges);
    bucket_csr_kernel<<<nb, 512, 0, stream>>>(bbase, bedge, row_ptr, sedge, n_nodes);

    // Precision prep: H -> fp8, W1/W2 -> swizzled bf16.
    tofp8_kernel<<<1024, 256, 0, stream>>>(H, Hf8, n_nodes * NFEAT / 8);
    wswizzle_kernel<<<32, 256, 0, stream>>>(W1, Wsw1, 64 * 128);
    wswizzle_kernel<<<64, 256, 0, stream>>>(W2, Wsw2, 128 * 128);

    // Layer 1: AHbf = bf16(A @ Hf8) ; H1f8 = fp8(relu(AHbf @ W1 + b1))
    spmm64_csr_f8<<<(n_nodes * 8 + 255) / 256, 256, 0, stream>>>(
        row_ptr, sedge, Hf8, AHbf, n_nodes);
    gemm_mfma_relu<64, 2><<<mfma_grid, 256, 0, stream>>>(
        AHbf, Wsw1, b1, H1f8, n_nodes);
    // Layer 2: AH1bf = bf16(A @ H1f8) ; H2 = relu(AH1bf @ W2 + b2) -> d_out
    spmm128_csr_f8<<<(n_nodes * 16 + 255) / 256, 256, 0, stream>>>(
        row_ptr, sedge, H1f8, AH1bf, n_nodes);
    gemm_mfma_relu<128, 0><<<mfma_grid, 256, 0, stream>>>(
        AH1bf, Wsw2, b2, out, n_nodes);
  } else {
    // ---- fallback: atomic scatter path (all f32) ----
    float* fAH = (float*)d_ws;
    float* fH1 = fAH + (size_t)n_nodes * NFEAT;
    hipMemsetAsync(fAH, 0, (size_t)n_nodes * NFEAT * sizeof(float), stream);
    hipMemsetAsync(out, 0, (size_t)n_nodes * NHID * sizeof(float), stream);
    spmm64_atomic<<<(n_edges * 16 + 255) / 256, 256, 0, stream>>>(row, col, vals, H, fAH, n_edges);
    gemm_tiled_relu<64><<<(n_nodes + 127) / 128, 256, 0, stream>>>(fAH, W1, b1, fH1, n_nodes);
    spmm128_atomic<<<(n_edges * 32 + 255) / 256, 256, 0, stream>>>(row, col, vals, fH1, out, n_edges);
    gemm_tiled_relu<128><<<(n_nodes + 127) / 128, 256, 0, stream>>>(out, W2, b2, out, n_nodes);
  }
}

// Round 10
// 279.397 us; speedup vs baseline: 16.2765x; 1.0408x over previous
//
#include <hip/hip_runtime.h>

// GCN: H2 = relu(A @ relu(A@H @ W1 + b1) @ W2 + b2)
// A: COO (row,col,vals), E=1.6M, N=100k, feats 64 -> 128 -> 128.
// R10: SpMM decode/accumulate in packed f32x2 (v_pk_fma_f32) -> -33% VALU
// issue; prep kernels fused. fp8 gather operands, f32 accumulate (R9).

#define NFEAT 64
#define NHID 128
#define BSHIFT 9              // 512 rows per bucket
#define BROWS (1 << BSHIFT)
#define NB_MAX 256            // supports n_nodes <= 131072 (17-bit col pack)

typedef __attribute__((ext_vector_type(8))) short bf16x8;
typedef __attribute__((ext_vector_type(4))) float f32x4;
typedef __attribute__((ext_vector_type(2))) float f32x2;

// ---------------- bf16 helpers ----------------
__device__ __forceinline__ unsigned short f2bf(float x) {
  unsigned u = __float_as_uint(x);
  unsigned r = (u + 0x7FFFu + ((u >> 16) & 1u)) >> 16;  // RNE
  return (unsigned short)r;
}
__device__ __forceinline__ unsigned pack2(float a, float b) {
  return (unsigned)f2bf(a) | ((unsigned)f2bf(b) << 16);
}

// ---------------- fp8 e4m3 helpers (HW cvt) ----------------
__device__ __forceinline__ unsigned pk_fp8x4(float a, float b, float c, float d) {
  int w = __builtin_amdgcn_cvt_pk_fp8_f32(a, b, 0, false);   // bytes 0,1
  w = __builtin_amdgcn_cvt_pk_fp8_f32(c, d, w, true);        // bytes 2,3
  return (unsigned)w;
}
__device__ __forceinline__ unsigned char f2fp8(float x) {
  return (unsigned char)(__builtin_amdgcn_cvt_pk_fp8_f32(x, 0.f, 0, false) & 0xFF);
}

// ---------------- fused prep: H->fp8, W1/W2 -> swizzled bf16 ----------------
// Work ids: [0, n8) fp8-pack (8 elems each); [n8, n8+8192) Wsw1; then Wsw2.
__global__ __launch_bounds__(256) void prep_kernel(
    const float* __restrict__ H, const float* __restrict__ W1,
    const float* __restrict__ W2, unsigned char* __restrict__ Hf8,
    unsigned short* __restrict__ Wsw1, unsigned short* __restrict__ Wsw2,
    int n8) {
  const int total = n8 + 64 * 128 + 128 * 128;
  for (int w = blockIdx.x * 256 + threadIdx.x; w < total; w += gridDim.x * 256) {
    if (w < n8) {
      float4 a = ((const float4*)H)[2 * w];
      float4 b = ((const float4*)H)[2 * w + 1];
      ((uint2*)Hf8)[w] = make_uint2(pk_fp8x4(a.x, a.y, a.z, a.w),
                                    pk_fp8x4(b.x, b.y, b.z, b.w));
    } else {
      int idx = w - n8;
      const float* W = W1;
      unsigned short* Wsw = Wsw1;
      if (idx >= 64 * 128) {
        idx -= 64 * 128;
        W = W2;
        Wsw = Wsw2;
      }
      int j = idx & 7, q = (idx >> 3) & 3, nn = (idx >> 5) & 127, kt = idx >> 12;
      int k = kt * 32 + q * 8 + j;
      Wsw[idx] = f2bf(W[(size_t)k * 128 + nn]);
    }
  }
}

// ---------------- bucket histogram (LDS-aggregated) ----------------
__global__ __launch_bounds__(256) void bhist_kernel(
    const int* __restrict__ row, int* __restrict__ bcnt, int n_edges, int nb) {
  __shared__ int h[NB_MAX];
  for (int i = threadIdx.x; i < NB_MAX; i += 256) h[i] = 0;
  __syncthreads();
  for (int e = blockIdx.x * 256 + threadIdx.x; e < n_edges; e += gridDim.x * 256)
    atomicAdd(&h[row[e] >> BSHIFT], 1);
  __syncthreads();
  for (int i = threadIdx.x; i < nb; i += 256)
    if (h[i]) atomicAdd(&bcnt[i], h[i]);
}

// ---------------- bucket scan -> bbase[nb+1], cur[nb], row_ptr[n] -----------
__global__ __launch_bounds__(NB_MAX) void bscan_kernel(
    const int* __restrict__ bcnt, int* __restrict__ bbase, int* __restrict__ cur,
    int* __restrict__ row_ptr, int nb, int n) {
  __shared__ int sm[NB_MAX];
  int t = threadIdx.x;
  int v = (t < nb) ? bcnt[t] : 0;
  sm[t] = v;
  __syncthreads();
  for (int off = 1; off < NB_MAX; off <<= 1) {
    int u = (t >= off) ? sm[t - off] : 0;
    __syncthreads();
    sm[t] += u;
    __syncthreads();
  }
  if (t < nb) {
    bbase[t] = sm[t] - v;
    cur[t] = sm[t] - v;
  }
  if (t == nb - 1) {
    bbase[nb] = sm[t];
    row_ptr[n] = sm[t];
  }
}

// ---------------- pass A: multi-split partition into buckets ----------------
__global__ __launch_bounds__(256) void partition_kernel(
    const int* __restrict__ row, const int* __restrict__ col,
    const float* __restrict__ vals, int* __restrict__ cur,
    int2* __restrict__ bedge, int n_edges) {
  __shared__ int h[NB_MAX], base[NB_MAX], rk[NB_MAX];
  for (int i = threadIdx.x; i < NB_MAX; i += 256) {
    h[i] = 0;
    rk[i] = 0;
  }
  __syncthreads();
  const int start = blockIdx.x * 256 + threadIdx.x;
  const int step = gridDim.x * 256;
  for (int e = start; e < n_edges; e += step)
    atomicAdd(&h[row[e] >> BSHIFT], 1);
  __syncthreads();
  for (int i = threadIdx.x; i < NB_MAX; i += 256)
    base[i] = h[i] ? atomicAdd(&cur[i], h[i]) : 0;
  __syncthreads();
  for (int e = start; e < n_edges; e += step) {
    int r = row[e];
    int b = r >> BSHIFT;
    int rl = r & (BROWS - 1);
    int p = base[b] + atomicAdd(&rk[b], 1);
    bedge[p] = make_int2((rl << 17) | col[e], __float_as_int(vals[e]));
  }
}

// ---------------- pass B: per-bucket exact CSR ----------------
__global__ __launch_bounds__(512) void bucket_csr_kernel(
    const int* __restrict__ bbase, const int2* __restrict__ bedge,
    int* __restrict__ row_ptr, int2* __restrict__ sedge, int n) {
  __shared__ int cnt[BROWS];
  __shared__ int sm[BROWS];
  const int b = blockIdx.x;
  const int t = threadIdx.x;
  const int beg = bbase[b], end = bbase[b + 1];
  cnt[t] = 0;
  __syncthreads();
  for (int j = beg + t; j < end; j += 512)
    atomicAdd(&cnt[((unsigned)bedge[j].x) >> 17], 1);
  __syncthreads();
  int v = cnt[t];
  sm[t] = v;
  __syncthreads();
  for (int off = 1; off < BROWS; off <<= 1) {
    int u = (t >= off) ? sm[t - off] : 0;
    __syncthreads();
    sm[t] += u;
    __syncthreads();
  }
  {
    int incl = sm[t];
    __syncthreads();
    sm[t] = incl - v;  // exclusive local base
  }
  int r = (b << BSHIFT) + t;
  if (r < n) row_ptr[r] = beg + sm[t];
  cnt[t] = 0;
  __syncthreads();
  for (int j = beg + t; j < end; j += 512) {
    int2 ev = bedge[j];
    int rl = ((unsigned)ev.x) >> 17;
    int rank = atomicAdd(&cnt[rl], 1);
    sedge[beg + sm[rl] + rank] = make_int2(ev.x & 0x1FFFF, ev.y);
  }
}

// ---------------- CSR gather SpMM, fp8 in / bf16 out, pk-f32 accum ----------
// 64 feats fp8 = 64 B/row: 8 lanes per row, one uint2 (8 fp8) per lane.
__global__ __launch_bounds__(256) void spmm64_csr_f8(
    const int* __restrict__ row_ptr, const int2* __restrict__ sedge,
    const unsigned char* __restrict__ Hf8, unsigned short* __restrict__ outbf,
    int n) {
  int tid = blockIdx.x * 256 + threadIdx.x;
  int r = tid >> 3;
  int f = tid & 7;
  if (r >= n) return;
  const uint2* Hq = (const uint2*)Hf8;  // 8 uint2 per 64-feat row
  int beg = row_ptr[r], end = row_ptr[r + 1];
  f32x2 a0 = {0.f, 0.f}, a1 = {0.f, 0.f}, a2 = {0.f, 0.f}, a3 = {0.f, 0.f};
#pragma unroll 2
  for (int j = beg; j < end; ++j) {
    int2 ev = sedge[j];
    float v = __int_as_float(ev.y);
    f32x2 vv = {v, v};
    uint2 q = Hq[ev.x * 8 + f];
    a0 += vv * __builtin_amdgcn_cvt_pk_f32_fp8(q.x, false);
    a1 += vv * __builtin_amdgcn_cvt_pk_f32_fp8(q.x, true);
    a2 += vv * __builtin_amdgcn_cvt_pk_f32_fp8(q.y, false);
    a3 += vv * __builtin_amdgcn_cvt_pk_f32_fp8(q.y, true);
  }
  ((uint4*)outbf)[(size_t)r * 8 + f] =
      make_uint4(pack2(a0.x, a0.y), pack2(a1.x, a1.y),
                 pack2(a2.x, a2.y), pack2(a3.x, a3.y));
}

// 128 feats fp8 = 128 B/row: 16 lanes per row.
__global__ __launch_bounds__(256) void spmm128_csr_f8(
    const int* __restrict__ row_ptr, const int2* __restrict__ sedge,
    const unsigned char* __restrict__ Hf8, unsigned short* __restrict__ outbf,
    int n) {
  int tid = blockIdx.x * 256 + threadIdx.x;
  int r = tid >> 4;
  int f = tid & 15;
  if (r >= n) return;
  const uint2* Hq = (const uint2*)Hf8;  // 16 uint2 per 128-feat row
  int beg = row_ptr[r], end = row_ptr[r + 1];
  f32x2 a0 = {0.f, 0.f}, a1 = {0.f, 0.f}, a2 = {0.f, 0.f}, a3 = {0.f, 0.f};
#pragma unroll 2
  for (int j = beg; j < end; ++j) {
    int2 ev = sedge[j];
    float v = __int_as_float(ev.y);
    f32x2 vv = {v, v};
    uint2 q = Hq[ev.x * 16 + f];
    a0 += vv * __builtin_amdgcn_cvt_pk_f32_fp8(q.x, false);
    a1 += vv * __builtin_amdgcn_cvt_pk_f32_fp8(q.x, true);
    a2 += vv * __builtin_amdgcn_cvt_pk_f32_fp8(q.y, false);
    a3 += vv * __builtin_amdgcn_cvt_pk_f32_fp8(q.y, true);
  }
  ((uint4*)outbf)[(size_t)r * 16 + f] =
      make_uint4(pack2(a0.x, a0.y), pack2(a1.x, a1.y),
                 pack2(a2.x, a2.y), pack2(a3.x, a3.y));
}

// ---------------- MFMA bf16 GEMM + bias + relu (LDS-free) ----------------
// OUT mode: 0 = f32, 2 = fp8 (for H1 consumed by spmm128_csr_f8).
template <int K, int OUTMODE>
__global__ __launch_bounds__(256) void gemm_mfma_relu(
    const unsigned short* __restrict__ Abf,
    const unsigned short* __restrict__ Wsw,
    const float* __restrict__ b, void* __restrict__ out_v, int n) {
  constexpr int KT = K / 32;
  const int lane = threadIdx.x & 63;
  const int wave = threadIdx.x >> 6;
  const int m = lane & 15;
  const int quad = lane >> 4;
  const int r0 = blockIdx.x * 64 + wave * 16;

  bf16x8 bfr[KT][8];
#pragma unroll
  for (int kt = 0; kt < KT; ++kt)
#pragma unroll
    for (int c = 0; c < 8; ++c)
      bfr[kt][c] = *(const bf16x8*)(Wsw + ((size_t)(kt * 128 + c * 16 + m)) * 32 + quad * 8);

  f32x4 acc[8];
#pragma unroll
  for (int c = 0; c < 8; ++c) acc[c] = (f32x4){0.f, 0.f, 0.f, 0.f};

  int row = r0 + m;
  if (row >= n) row = n - 1;
  const uint4* Arow = (const uint4*)(Abf + (size_t)row * K);
#pragma unroll
  for (int kt = 0; kt < KT; ++kt) {
    bf16x8 a = *(const bf16x8*)&Arow[kt * 4 + quad];
#pragma unroll
    for (int c = 0; c < 8; ++c)
      acc[c] = __builtin_amdgcn_mfma_f32_16x16x32_bf16(a, bfr[kt][c], acc[c], 0, 0, 0);
  }

#pragma unroll
  for (int c = 0; c < 8; ++c) {
    float bias = b[c * 16 + m];
#pragma unroll
    for (int i = 0; i < 4; ++i) {
      int rr = r0 + quad * 4 + i;
      if (rr >= n) continue;
      float v = fmaxf(acc[c][i] + bias, 0.f);
      if (OUTMODE == 2)
        ((unsigned char*)out_v)[(size_t)rr * 128 + c * 16 + m] = f2fp8(v);
      else
        ((float*)out_v)[(size_t)rr * 128 + c * 16 + m] = v;
    }
  }
}

// ---------------- fallback path (f32 atomics + f32 VALU GEMM) ----------------
__global__ __launch_bounds__(256) void spmm64_atomic(
    const int* __restrict__ row, const int* __restrict__ col,
    const float* __restrict__ vals, const float* __restrict__ Hin,
    float* __restrict__ out, int n_edges) {
  int tid = blockIdx.x * 256 + threadIdx.x;
  int e = tid >> 4, f = tid & 15;
  if (e >= n_edges) return;
  int c = col[e], r = row[e];
  float v = vals[e];
  float4 h = ((const float4*)Hin)[(size_t)c * 16 + f];
  float* o = out + (size_t)r * 64 + f * 4;
  atomicAdd(o + 0, v * h.x);
  atomicAdd(o + 1, v * h.y);
  atomicAdd(o + 2, v * h.z);
  atomicAdd(o + 3, v * h.w);
}

__global__ __launch_bounds__(256) void spmm128_atomic(
    const int* __restrict__ row, const int* __restrict__ col,
    const float* __restrict__ vals, const float* __restrict__ Hin,
    float* __restrict__ out, int n_edges) {
  int tid = blockIdx.x * 256 + threadIdx.x;
  int e = tid >> 5, f = tid & 31;
  if (e >= n_edges) return;
  int c = col[e], r = row[e];
  float v = vals[e];
  float4 h = ((const float4*)Hin)[(size_t)c * 32 + f];
  float* o = out + (size_t)r * 128 + f * 4;
  atomicAdd(o + 0, v * h.x);
  atomicAdd(o + 1, v * h.y);
  atomicAdd(o + 2, v * h.z);
  atomicAdd(o + 3, v * h.w);
}

template <int K>
__global__ __launch_bounds__(256) void gemm_tiled_relu(
    const float* __restrict__ A, const float* __restrict__ W,
    const float* __restrict__ b, float* __restrict__ out, int n) {
  constexpr int KB = 32;
  constexpr int RP = 132;
  __shared__ float As[KB][RP];
  __shared__ float Ws[KB][128];
  const int t = threadIdx.x;
  const int tx = t & 15, ty = t >> 4;
  const int r0 = blockIdx.x * 128;
  float4 acc0[8], acc1[8];
#pragma unroll
  for (int i = 0; i < 8; ++i) {
    acc0[i] = make_float4(0.f, 0.f, 0.f, 0.f);
    acc1[i] = make_float4(0.f, 0.f, 0.f, 0.f);
  }
  for (int k0 = 0; k0 < K; k0 += KB) {
#pragma unroll
    for (int q = 0; q < 4; ++q) {
      int f = q * 256 + t;
      int kk = f >> 5, cv = f & 31;
      ((float4*)&Ws[kk][0])[cv] = ((const float4*)(W + (size_t)(k0 + kk) * 128))[cv];
    }
#pragma unroll
    for (int q = 0; q < 4; ++q) {
      int f = q * 256 + t;
      int r = f >> 3, kv = f & 7;
      float4 av = make_float4(0.f, 0.f, 0.f, 0.f);
      if (r0 + r < n) av = ((const float4*)(A + (size_t)(r0 + r) * K + k0))[kv];
      As[4 * kv + 0][r] = av.x;
      As[4 * kv + 1][r] = av.y;
      As[4 * kv + 2][r] = av.z;
      As[4 * kv + 3][r] = av.w;
    }
    __syncthreads();
#pragma unroll
    for (int k = 0; k < KB; ++k) {
      float4 w0 = *((const float4*)&Ws[k][4 * tx]);
      float4 w1 = *((const float4*)&Ws[k][64 + 4 * tx]);
#pragma unroll
      for (int i = 0; i < 8; ++i) {
        float a = As[k][ty + 16 * i];
        acc0[i].x = fmaf(a, w0.x, acc0[i].x);
        acc0[i].y = fmaf(a, w0.y, acc0[i].y);
        acc0[i].z = fmaf(a, w0.z, acc0[i].z);
        acc0[i].w = fmaf(a, w0.w, acc0[i].w);
        acc1[i].x = fmaf(a, w1.x, acc1[i].x);
        acc1[i].y = fmaf(a, w1.y, acc1[i].y);
        acc1[i].z = fmaf(a, w1.z, acc1[i].z);
        acc1[i].w = fmaf(a, w1.w, acc1[i].w);
      }
    }
    __syncthreads();
  }
  float4 bb0 = ((const float4*)b)[tx];
  float4 bb1 = ((const float4*)(b + 64))[tx];
#pragma unroll
  for (int i = 0; i < 8; ++i) {
    int r = r0 + ty + 16 * i;
    if (r >= n) continue;
    float4 o0, o1;
    o0.x = fmaxf(acc0[i].x + bb0.x, 0.f);
    o0.y = fmaxf(acc0[i].y + bb0.y, 0.f);
    o0.z = fmaxf(acc0[i].z + bb0.z, 0.f);
    o0.w = fmaxf(acc0[i].w + bb0.w, 0.f);
    o1.x = fmaxf(acc1[i].x + bb1.x, 0.f);
    o1.y = fmaxf(acc1[i].y + bb1.y, 0.f);
    o1.z = fmaxf(acc1[i].z + bb1.z, 0.f);
    o1.w = fmaxf(acc1[i].w + bb1.w, 0.f);
    ((float4*)(out + (size_t)r * 128))[tx] = o0;
    ((float4*)(out + (size_t)r * 128 + 64))[tx] = o1;
  }
}

extern "C" void kernel_launch(void* const* d_in, const int* in_sizes, int n_in,
                              void* d_out, int out_size, void* d_ws, size_t ws_size,
                              hipStream_t stream) {
  const int* row = (const int*)d_in[0];
  const int* col = (const int*)d_in[1];
  const float* vals = (const float*)d_in[2];
  const float* H = (const float*)d_in[3];
  const float* W1 = (const float*)d_in[4];
  const float* b1 = (const float*)d_in[5];
  const float* W2 = (const float*)d_in[6];
  const float* b2 = (const float*)d_in[7];
  float* out = (float*)d_out;

  const int n_edges = in_sizes[0];
  const int n_nodes = in_sizes[3] / NFEAT;
  const int nb = (n_nodes + BROWS - 1) / BROWS;
  const int mfma_grid = (n_nodes + 63) / 64;

  // Workspace layout (CSR path):
  // slab0: max(bedge E*8, AH1bf N*128*2)  -- bedge dead before AH1bf written
  // | Hf8 N*64 | H1f8 N*128 | AHbf N*64*2 | sedge E*8
  // | Wsw1 | Wsw2 | bcnt | bbase | cur | row_ptr
  size_t off = 0;
  char* base = (char*)d_ws;
  char* slab0 = base;
  size_t slab0_sz = (size_t)n_edges * 8;
  size_t ah1_sz = (size_t)n_nodes * NHID * 2;
  if (ah1_sz > slab0_sz) slab0_sz = ah1_sz;
  off += slab0_sz;
  unsigned char* Hf8 = (unsigned char*)(base + off);   off += (size_t)n_nodes * NFEAT;
  unsigned char* H1f8 = (unsigned char*)(base + off);  off += (size_t)n_nodes * NHID;
  unsigned short* AHbf = (unsigned short*)(base + off); off += (size_t)n_nodes * NFEAT * 2;
  int2* sedge = (int2*)(base + off);  off += (size_t)n_edges * 8;
  unsigned short* Wsw1 = (unsigned short*)(base + off); off += 64 * 128 * 2;
  unsigned short* Wsw2 = (unsigned short*)(base + off); off += 128 * 128 * 2;
  int* bcnt = (int*)(base + off);     off += NB_MAX * 4;
  int* bbase = (int*)(base + off);    off += (NB_MAX + 1) * 4;
  int* cur = (int*)(base + off);      off += NB_MAX * 4;
  int* row_ptr = (int*)(base + off);  off += ((size_t)n_nodes + 1) * 4;
  const size_t needed = off;
  int2* bedge = (int2*)slab0;
  unsigned short* AH1bf = (unsigned short*)slab0;

  if (ws_size >= needed && nb <= NB_MAX && n_nodes <= (1 << 17)) {
    // ---- bucket-sort CSR build ----
    hipMemsetAsync(bcnt, 0, NB_MAX * sizeof(int), stream);
    bhist_kernel<<<256, 256, 0, stream>>>(row, bcnt, n_edges, nb);
    bscan_kernel<<<1, NB_MAX, 0, stream>>>(bcnt, bbase, cur, row_ptr, nb, n_nodes);
    partition_kernel<<<256, 256, 0, stream>>>(row, col, vals, cur, bedge, n_edges);
    bucket_csr_kernel<<<nb, 512, 0, stream>>>(bbase, bedge, row_ptr, sedge, n_nodes);

    // Fused prep: H -> fp8, W1/W2 -> swizzled bf16.
    prep_kernel<<<1024, 256, 0, stream>>>(H, W1, W2, Hf8, Wsw1, Wsw2,
                                          n_nodes * NFEAT / 8);

    // Layer 1: AHbf = bf16(A @ Hf8) ; H1f8 = fp8(relu(AHbf @ W1 + b1))
    spmm64_csr_f8<<<(n_nodes * 8 + 255) / 256, 256, 0, stream>>>(
        row_ptr, sedge, Hf8, AHbf, n_nodes);
    gemm_mfma_relu<64, 2><<<mfma_grid, 256, 0, stream>>>(
        AHbf, Wsw1, b1, H1f8, n_nodes);
    // Layer 2: AH1bf = bf16(A @ H1f8) ; H2 = relu(AH1bf @ W2 + b2) -> d_out
    spmm128_csr_f8<<<(n_nodes * 16 + 255) / 256, 256, 0, stream>>>(
        row_ptr, sedge, H1f8, AH1bf, n_nodes);
    gemm_mfma_relu<128, 0><<<mfma_grid, 256, 0, stream>>>(
        AH1bf, Wsw2, b2, out, n_nodes);
  } else {
    // ---- fallback: atomic scatter path (all f32) ----
    float* fAH = (float*)d_ws;
    float* fH1 = fAH + (size_t)n_nodes * NFEAT;
    hipMemsetAsync(fAH, 0, (size_t)n_nodes * NFEAT * sizeof(float), stream);
    hipMemsetAsync(out, 0, (size_t)n_nodes * NHID * sizeof(float), stream);
    spmm64_atomic<<<(n_edges * 16 + 255) / 256, 256, 0, stream>>>(row, col, vals, H, fAH, n_edges);
    gemm_tiled_relu<64><<<(n_nodes + 127) / 128, 256, 0, stream>>>(fAH, W1, b1, fH1, n_nodes);
    spmm128_atomic<<<(n_edges * 32 + 255) / 256, 256, 0, stream>>>(row, col, vals, fH1, out, n_edges);
    gemm_tiled_relu<128><<<(n_nodes + 127) / 128, 256, 0, stream>>>(out, W2, b2, out, n_nodes);
  }
}